// Round 3
// baseline (1442.008 us; speedup 1.0000x reference)
//
#include <hip/hip_runtime.h>
#include <hip/hip_bf16.h>

// ---------------------------------------------------------------------------
// 1x1 conv as GEMM: out[b,o,p] = sum_i w(o,i) * in[b,i,p]
// wio==0: w[o*I+i] ('oi');  wio==1: w[i*O+o] ('io').  OT outputs per thread.
// ---------------------------------------------------------------------------
template<int OT>
__global__ __launch_bounds__(256) void conv1x1_kernel(
    const float* __restrict__ in, const float* __restrict__ w,
    float* __restrict__ out, int I, int O, int P, int wio)
{
  int p  = blockIdx.x*256 + threadIdx.x;
  if(p >= P) return;
  int o0 = blockIdx.y*OT;
  int b  = blockIdx.z;
  const float* inb = in + (size_t)b*I*P + p;
  float acc[OT];
#pragma unroll
  for(int j=0;j<OT;j++) acc[j]=0.f;
  for(int i=0;i<I;i++){
    float v = inb[(size_t)i*P];
#pragma unroll
    for(int j=0;j<OT;j++){
      float wv = wio ? w[(size_t)i*O + o0 + j] : w[(size_t)(o0+j)*I + i];
      acc[j] = fmaf(wv, v, acc[j]);
    }
  }
  float* ob = out + ((size_t)b*O + o0)*P + p;
#pragma unroll
  for(int j=0;j<OT;j++) ob[(size_t)j*P] = acc[j];
}

// ---------------------------------------------------------------------------
// BatchNorm training-mode stats per channel over (B,HW). mr[2c]=mean, mr[2c+1]=rstd
// ---------------------------------------------------------------------------
__global__ __launch_bounds__(256) void bn_stats_kernel(
    const float* __restrict__ x, float* __restrict__ mr, int B, int C, int P)
{
  int c = blockIdx.x;
  int tid = threadIdx.x;
  int tot = B*P;
  float s=0.f, s2=0.f;
  for(int idx=tid; idx<tot; idx+=256){
    int b = idx / P; int p = idx - b*P;
    float v = x[((size_t)b*C + c)*P + p];
    s += v; s2 += v*v;
  }
  __shared__ float ls[256], ls2[256];
  ls[tid]=s; ls2[tid]=s2;
  __syncthreads();
  for(int st=128; st>0; st>>=1){
    if(tid<st){ ls[tid]+=ls[tid+st]; ls2[tid]+=ls2[tid+st]; }
    __syncthreads();
  }
  if(tid==0){
    float m = ls[0]/(float)tot;
    float var = ls2[0]/(float)tot - m*m;   // biased variance, as reference
    mr[2*c]   = m;
    mr[2*c+1] = rsqrtf(var + 1e-5f);
  }
}

__global__ __launch_bounds__(256) void bn_apply_relu_kernel(
    const float* __restrict__ in, float* __restrict__ out,
    const float* __restrict__ mr, int C, int P, int total)
{
  int idx = blockIdx.x*256 + threadIdx.x;
  if(idx >= total) return;
  int c = (idx / P) % C;
  float v = (in[idx] - mr[2*c]) * mr[2*c+1];
  out[idx] = v > 0.f ? v : 0.f;
}

// ---------------------------------------------------------------------------
// k=2 s=2 conv (encoder downsample), C->C, w[o,c,p,q]
// ---------------------------------------------------------------------------
__global__ __launch_bounds__(256) void conv2x2s2_kernel(
    const float* __restrict__ in, const float* __restrict__ w,
    float* __restrict__ out, int C, int Ho, int Wo)
{
  int idx = blockIdx.x*256 + threadIdx.x;
  int o = blockIdx.y, b = blockIdx.z;
  if(idx >= Ho*Wo) return;
  int h = idx / Wo, ww = idx - h*Wo;
  int Hi = 2*Ho, Wi = 2*Wo;
  const float* inb = in + (size_t)b*C*Hi*Wi;
  float acc = 0.f;
  for(int i=0;i<C;i++){
    const float* r = inb + (size_t)i*Hi*Wi + (2*h)*Wi + 2*ww;
    const float* wp = w + ((size_t)o*C + i)*4;
    acc += wp[0]*r[0] + wp[1]*r[1] + wp[2]*r[Wi] + wp[3]*r[Wi+1];
  }
  out[((size_t)b*C + o)*Ho*Wo + idx] = acc;
}

// ---------------------------------------------------------------------------
// depthwise 3x3, pad 1. w[c,0,3,3]
// ---------------------------------------------------------------------------
__global__ __launch_bounds__(256) void dwconv3x3_kernel(
    const float* __restrict__ in, const float* __restrict__ w,
    float* __restrict__ out, int C, int H, int Wd)
{
  int idx = blockIdx.x*256 + threadIdx.x;
  int c = blockIdx.y, b = blockIdx.z;
  if(idx >= H*Wd) return;
  int h = idx / Wd, x = idx - h*Wd;
  const float* inp = in + ((size_t)b*C + c)*H*Wd;
  float acc = 0.f;
#pragma unroll
  for(int p=0;p<3;p++){
    int hh = h + p - 1;
    if((unsigned)hh >= (unsigned)H) continue;
#pragma unroll
    for(int q=0;q<3;q++){
      int wv = x + q - 1;
      if((unsigned)wv >= (unsigned)Wd) continue;
      acc += w[c*9 + p*3 + q] * inp[hh*Wd + wv];
    }
  }
  out[((size_t)b*C + c)*H*Wd + idx] = acc;
}

// ---------------------------------------------------------------------------
// full 3x3 conv, pad 1, IC<=64, O = gridDim.y. w[o,i,3,3]
// ---------------------------------------------------------------------------
__global__ __launch_bounds__(256) void conv3x3_kernel(
    const float* __restrict__ in, const float* __restrict__ w,
    float* __restrict__ out, int IC, int H, int Wd)
{
  int o = blockIdx.y, b = blockIdx.z;
  __shared__ float wl[576];
  for(int t=threadIdx.x; t<IC*9; t+=256) wl[t] = w[(size_t)o*IC*9 + t];
  __syncthreads();
  int idx = blockIdx.x*256 + threadIdx.x;
  if(idx >= H*Wd) return;
  int h = idx / Wd, x = idx - h*Wd;
  const float* inb = in + (size_t)b*IC*H*Wd;
  float acc = 0.f;
  for(int i=0;i<IC;i++){
    const float* inp = inb + (size_t)i*H*Wd;
    const float* wp  = wl + i*9;
#pragma unroll
    for(int p=0;p<3;p++){
      int hh = h + p - 1;
      if((unsigned)hh >= (unsigned)H) continue;
      const float* row = inp + hh*Wd;
#pragma unroll
      for(int q=0;q<3;q++){
        int wv = x + q - 1;
        if((unsigned)wv >= (unsigned)Wd) continue;
        acc = fmaf(wp[p*3+q], row[wv], acc);
      }
    }
  }
  out[((size_t)b*gridDim.y + o)*H*Wd + idx] = acc;
}

// ---------------------------------------------------------------------------
// ConvTranspose k=2 s=2 upsample. w[i,o,p,q]; OT out-channels per thread.
// ---------------------------------------------------------------------------
template<int OT>
__global__ __launch_bounds__(256) void upsample2x2_kernel(
    const float* __restrict__ in, const float* __restrict__ w,
    float* __restrict__ out, int I, int O, int H, int Wd)
{
  int idx = blockIdx.x*256 + threadIdx.x;
  int o0 = blockIdx.y*OT, b = blockIdx.z;
  if(idx >= H*Wd) return;
  int h = idx / Wd, x = idx - h*Wd;
  const float* inb = in + (size_t)b*I*H*Wd + idx;
  float acc[OT][4];
#pragma unroll
  for(int j=0;j<OT;j++){ acc[j][0]=acc[j][1]=acc[j][2]=acc[j][3]=0.f; }
  for(int i=0;i<I;i++){
    float v = inb[(size_t)i*H*Wd];
#pragma unroll
    for(int j=0;j<OT;j++){
      const float* wp = w + ((size_t)i*O + o0 + j)*4;
      acc[j][0] = fmaf(wp[0], v, acc[j][0]);
      acc[j][1] = fmaf(wp[1], v, acc[j][1]);
      acc[j][2] = fmaf(wp[2], v, acc[j][2]);
      acc[j][3] = fmaf(wp[3], v, acc[j][3]);
    }
  }
  int W2 = 2*Wd;
#pragma unroll
  for(int j=0;j<OT;j++){
    float* ob = out + ((size_t)b*O + o0 + j)*(4*(size_t)H*Wd);
    ob[(2*h)*W2 + 2*x]       = acc[j][0];
    ob[(2*h)*W2 + 2*x + 1]   = acc[j][1];
    ob[(2*h+1)*W2 + 2*x]     = acc[j][2];
    ob[(2*h+1)*W2 + 2*x + 1] = acc[j][3];
  }
}

// ---------------------------------------------------------------------------
// F.normalize(dim=-1): 512 rows (b in 0..7, c in 0..63), row length 1024.
// CB = per-batch channel stride (64 for q, 128 for kv; only first 64 normed).
// ---------------------------------------------------------------------------
__global__ __launch_bounds__(256) void l2norm_kernel(float* __restrict__ x, int CB)
{
  int r = blockIdx.x;
  int b = r >> 6, c = r & 63;
  float* p = x + ((size_t)b*CB + c)*1024;
  int tid = threadIdx.x;
  float s = 0.f;
  for(int i=tid;i<1024;i+=256){ float v=p[i]; s += v*v; }
  __shared__ float ls[256];
  ls[tid]=s; __syncthreads();
  for(int st=128; st>0; st>>=1){ if(tid<st) ls[tid]+=ls[tid+st]; __syncthreads(); }
  float scale = 1.f / fmaxf(sqrtf(ls[0]), 1e-12f);
  for(int i=tid;i<1024;i+=256) p[i] *= scale;
}

// ---------------------------------------------------------------------------
// Spatial attention pass 1: per row n compute max_m and 1/sum_m exp.
// q: (b,64,1024); kv: (b,128,1024), k = channels 0..63. grid (4,8,8). 32KB LDS.
// ---------------------------------------------------------------------------
__global__ __launch_bounds__(256) void attn_pass1(
    const float* __restrict__ q, const float* __restrict__ kv,
    const float* __restrict__ temp,
    float* __restrict__ mx_out, float* __restrict__ iden_out)
{
  int chunk = blockIdx.x, hh = blockIdx.y, b = blockIdx.z;
  int tid = threadIdx.x;
  __shared__ __align__(16) float kl[8192];          // [m][c], c=0..7
  const float* kb = kv + ((size_t)b*128 + hh*8)*1024;
  for(int t=tid;t<8192;t+=256){ int c=t>>10, m=t&1023; kl[m*8+c]=kb[t]; }
  __syncthreads();
  int n = chunk*256 + tid;
  const float* qp = q + ((size_t)b*64 + hh*8)*1024 + n;
  float qr[8];
#pragma unroll
  for(int c=0;c<8;c++) qr[c]=qp[(size_t)c*1024];
  float th = temp[hh];
  const float4* kl4 = (const float4*)kl;
  float mx = -3.4e38f;
  for(int m=0;m<1024;m++){
    float4 a = kl4[2*m], a2 = kl4[2*m+1];
    float s = qr[0]*a.x+qr[1]*a.y+qr[2]*a.z+qr[3]*a.w
            + qr[4]*a2.x+qr[5]*a2.y+qr[6]*a2.z+qr[7]*a2.w;
    mx = fmaxf(mx, s*th);
  }
  float den = 0.f;
  for(int m=0;m<1024;m++){
    float4 a = kl4[2*m], a2 = kl4[2*m+1];
    float s = qr[0]*a.x+qr[1]*a.y+qr[2]*a.z+qr[3]*a.w
            + qr[4]*a2.x+qr[5]*a2.y+qr[6]*a2.z+qr[7]*a2.w;
    den += __expf(s*th - mx);
  }
  int bh = b*8+hh;
  mx_out[(size_t)bh*1024+n]   = mx;
  iden_out[(size_t)bh*1024+n] = 1.f/den;
}

// ---------------------------------------------------------------------------
// Spatial attention pass 2: out[c,m] = sum_n softmax(S)[n,m]*v[c,n].
// Processes n in two halves of 512 so LDS stays at 32KB. grid (4,8,8).
// ---------------------------------------------------------------------------
__global__ __launch_bounds__(256) void attn_pass2(
    const float* __restrict__ q, const float* __restrict__ kv,
    const float* __restrict__ temp,
    const float* __restrict__ mx_in, const float* __restrict__ iden_in,
    float* __restrict__ out)
{
  int chunk = blockIdx.x, hh = blockIdx.y, b = blockIdx.z;
  int tid = threadIdx.x;
  __shared__ __align__(16) float ql[4096];   // [n][c], 512 n per half
  __shared__ __align__(16) float vl[4096];
  const float* qb = q  + ((size_t)b*64 + hh*8)*1024;
  const float* vb = kv + ((size_t)b*128 + 64 + hh*8)*1024;
  int bh = b*8+hh;
  int m = chunk*256 + tid;
  const float* kb = kv + ((size_t)b*128 + hh*8)*1024 + m;
  float kr[8];
#pragma unroll
  for(int c=0;c<8;c++) kr[c]=kb[(size_t)c*1024];
  float th = temp[hh];
  const float* mxp = mx_in  + (size_t)bh*1024;
  const float* idp = iden_in + (size_t)bh*1024;
  float acc[8] = {0,0,0,0,0,0,0,0};
  for(int half=0; half<2; half++){
    int n0 = half*512;
    __syncthreads();
    for(int t=tid; t<4096; t+=256){
      int c = t>>9, n = t&511;
      ql[n*8+c] = qb[(size_t)c*1024 + n0 + n];
      vl[n*8+c] = vb[(size_t)c*1024 + n0 + n];
    }
    __syncthreads();
    const float4* ql4 = (const float4*)ql;
    const float4* vl4 = (const float4*)vl;
    for(int n=0;n<512;n++){
      float4 qa = ql4[2*n], qa2 = ql4[2*n+1];
      float s = kr[0]*qa.x+kr[1]*qa.y+kr[2]*qa.z+kr[3]*qa.w
              + kr[4]*qa2.x+kr[5]*qa2.y+kr[6]*qa2.z+kr[7]*qa2.w;
      float pp = __expf(s*th - mxp[n0+n]) * idp[n0+n];
      float4 va = vl4[2*n], va2 = vl4[2*n+1];
      acc[0]+=pp*va.x; acc[1]+=pp*va.y; acc[2]+=pp*va.z; acc[3]+=pp*va.w;
      acc[4]+=pp*va2.x; acc[5]+=pp*va2.y; acc[6]+=pp*va2.z; acc[7]+=pp*va2.w;
    }
  }
  float* ob = out + ((size_t)b*64 + hh*8)*1024 + m;
#pragma unroll
  for(int c=0;c<8;c++) ob[(size_t)c*1024] = acc[c];
}

// ---------------------------------------------------------------------------
// Channel attention (8x8 gram per b,head), accumulates (+=) into out. grid (8,8)
// ---------------------------------------------------------------------------
__global__ __launch_bounds__(256) void attn_channel(
    const float* __restrict__ q, const float* __restrict__ kv,
    const float* __restrict__ temp, float* out)
{
  int hh = blockIdx.x, b = blockIdx.y;
  __shared__ float kl[8192];
  const float* qb = q  + ((size_t)b*64 + hh*8)*1024;
  const float* kb = kv + ((size_t)b*128 + hh*8)*1024;
  const float* vb = kv + ((size_t)b*128 + 64 + hh*8)*1024;
  int tid = threadIdx.x;
  for(int t=tid;t<8192;t+=256) kl[t]=kb[t];
  __syncthreads();
  __shared__ float g[64], a[64];
  if(tid < 64){
    int c = tid >> 3, d = tid & 7;
    float s = 0.f;
    for(int n=0;n<1024;n++) s += qb[(size_t)c*1024+n]*kl[d*1024+n];
    g[tid] = s * temp[hh];
  }
  __syncthreads();
  if(tid < 8){
    float mx = -3.4e38f;
    for(int d=0;d<8;d++) mx = fmaxf(mx, g[tid*8+d]);
    float den = 0.f;
    for(int d=0;d<8;d++){ float e = __expf(g[tid*8+d]-mx); a[tid*8+d]=e; den+=e; }
    float inv = 1.f/den;
    for(int d=0;d<8;d++) a[tid*8+d] *= inv;
  }
  __syncthreads();
  float* ob = out + ((size_t)b*64 + hh*8)*1024;
  for(int n=tid;n<1024;n+=256){
    float vv[8];
#pragma unroll
    for(int d=0;d<8;d++) vv[d] = vb[(size_t)d*1024+n];
#pragma unroll
    for(int c=0;c<8;c++){
      float s = 0.f;
#pragma unroll
      for(int d=0;d<8;d++) s += a[c*8+d]*vv[d];
      ob[(size_t)c*1024+n] += s;
    }
  }
}

// ---------------------------------------------------------------------------
extern "C" void kernel_launch(void* const* d_in, const int* in_sizes, int n_in,
                              void* d_out, int out_size, void* d_ws, size_t ws_size,
                              hipStream_t stream)
{
  (void)in_sizes; (void)n_in; (void)out_size; (void)ws_size;
  // Reference dtypes are all float32.
  const float* x      = (const float*)d_in[0];
  const float* y      = (const float*)d_in[1];
  const float* temp   = (const float*)d_in[2];
  const float* enc_w1 = (const float*)d_in[3];
  const float* enc_w2 = (const float*)d_in[4];
  const float* enc_w3 = (const float*)d_in[5];
  const float* kv_w   = (const float*)d_in[6];
  const float* kv_dw_w= (const float*)d_in[7];
  const float* q_w    = (const float*)d_in[8];
  const float* q_dw_w = (const float*)d_in[9];
  const float* proj_w = (const float*)d_in[10];
  const float* dec_w1 = (const float*)d_in[11];
  const float* dec_w2 = (const float*)d_in[12];
  const float* dec_w3 = (const float*)d_in[13];
  float* out = (float*)d_out;

  // Workspace layout (float offsets). Peak = 5,374,464 floats = 21.5 MB.
  float* W    = (float*)d_ws;
  float* BUF1 = W;                    // 1,048,576 f  (e1 / kv_pre / q_pre tmp / d1)
  float* BUF2 = W + 1048576;          //   262,144 f  (e2)
  float* XE   = W + 1310720;          //   524,288 f  (x-encoded / q_pre / proj out)
  float* YE   = W + 1835008;          //   524,288 f  (y-encoded / attn out)
  float* KV   = W + 2359296;          // 1,048,576 f  (k|v; k l2-normed in place)
  float* Q    = W + 3407872;          //   524,288 f
  // D2 (decoder mid, 4,194,304 f) overlaps BUF2..Q — all dead by decoder time.
  float* D2   = W + 1048576;          // ..5,242,880
  float* MX   = W + 5242880;          //    65,536 f
  float* IDEN = W + 5308416;          //    65,536 f
  float* ST   = W + 5373952;          //       512 f  (bn mean/rstd pairs)
  // D3 (decoder pre-BN, 8,388,608 f) lives in d_out; final BN runs in-place.

  // ---- shared encoder applied to x then y ----
  const float* srcs[2] = {x, y};
  float* dsts[2] = {XE, YE};
  for(int t=0;t<2;t++){
    conv1x1_kernel<4><<<dim3(16,8,8),256,0,stream>>>(srcs[t], enc_w1, BUF1, 256, 32, 4096, 0);
    bn_stats_kernel<<<32,256,0,stream>>>(BUF1, ST, 8, 32, 4096);
    bn_apply_relu_kernel<<<4096,256,0,stream>>>(BUF1, BUF1, ST, 32, 4096, 1048576);
    conv2x2s2_kernel<<<dim3(4,32,8),256,0,stream>>>(BUF1, enc_w2, BUF2, 32, 32, 32);
    bn_stats_kernel<<<32,256,0,stream>>>(BUF2, ST, 8, 32, 1024);
    bn_apply_relu_kernel<<<1024,256,0,stream>>>(BUF2, BUF2, ST, 32, 1024, 262144);
    conv1x1_kernel<4><<<dim3(4,16,8),256,0,stream>>>(BUF2, enc_w3, dsts[t], 32, 64, 1024, 0);
    bn_stats_kernel<<<64,256,0,stream>>>(dsts[t], ST, 8, 64, 1024);
    bn_apply_relu_kernel<<<2048,256,0,stream>>>(dsts[t], dsts[t], ST, 64, 1024, 524288);
  }

  // ---- kv = dw3x3(1x1(XE));  q = conv3x3(1x1(YE)) ----
  conv1x1_kernel<4><<<dim3(4,32,8),256,0,stream>>>(XE, kv_w, BUF1, 64, 128, 1024, 0);
  dwconv3x3_kernel<<<dim3(4,128,8),256,0,stream>>>(BUF1, kv_dw_w, KV, 128, 32, 32);
  conv1x1_kernel<4><<<dim3(4,16,8),256,0,stream>>>(YE, q_w, XE, 64, 64, 1024, 0);
  conv3x3_kernel<<<dim3(4,64,8),256,0,stream>>>(XE, q_dw_w, Q, 64, 32, 32);

  // ---- l2 normalize q and k along hw ----
  l2norm_kernel<<<512,256,0,stream>>>(Q, 64);
  l2norm_kernel<<<512,256,0,stream>>>(KV, 128);

  // ---- attention: spatial (2-pass) + channel, accumulated into YE ----
  attn_pass1<<<dim3(4,8,8),256,0,stream>>>(Q, KV, temp, MX, IDEN);
  attn_pass2<<<dim3(4,8,8),256,0,stream>>>(Q, KV, temp, MX, IDEN, YE);
  attn_channel<<<dim3(8,8),256,0,stream>>>(Q, KV, temp, YE);

  // ---- proj (linear => proj(out_s + out_c)) ----
  conv1x1_kernel<4><<<dim3(4,16,8),256,0,stream>>>(YE, proj_w, XE, 64, 64, 1024, 0);

  // ---- decoder ----
  conv1x1_kernel<4><<<dim3(4,32,8),256,0,stream>>>(XE, dec_w1, BUF1, 64, 128, 1024, 1);
  bn_stats_kernel<<<128,256,0,stream>>>(BUF1, ST, 8, 128, 1024);
  bn_apply_relu_kernel<<<4096,256,0,stream>>>(BUF1, BUF1, ST, 128, 1024, 1048576);

  upsample2x2_kernel<4><<<dim3(4,32,8),256,0,stream>>>(BUF1, dec_w2, D2, 128, 128, 32, 32);
  bn_stats_kernel<<<128,256,0,stream>>>(D2, ST, 8, 128, 4096);
  bn_apply_relu_kernel<<<16384,256,0,stream>>>(D2, D2, ST, 128, 4096, 4194304);

  conv1x1_kernel<8><<<dim3(16,32,8),256,0,stream>>>(D2, dec_w3, out, 128, 256, 4096, 1);
  bn_stats_kernel<<<256,256,0,stream>>>(out, ST, 8, 256, 4096);
  bn_apply_relu_kernel<<<32768,256,0,stream>>>(out, out, ST, 256, 4096, 8388608);
}

// Round 4
// 900.338 us; speedup vs baseline: 1.6016x; 1.6016x over previous
//
#include <hip/hip_runtime.h>
#include <hip/hip_bf16.h>

#define EPS_BN 1e-5f

// ===========================================================================
// Tiled 1x1 conv (GEMM): out[z,o,p] = sum_i w(o,i) * in[z,i,p]
//  - block: 256 threads, each handles 4 consecutive cols (float4) x OT outputs
//  - grid: (P/1024, O/OT, Z). P must be a multiple of 1024.
//  - weights staged in LDS; optional BN+ReLU applied on load (from raw sums);
//    optional per-channel sum/sumsq accumulated to stOut via atomics.
//  - two-tensor batching: z >= zsplit reads in1, tensor index t for stats.
// ===========================================================================
template<int OT, bool HASBN, bool HASSTATS>
__global__ __launch_bounds__(256) void conv1x1_kernel(
    const float* __restrict__ in0, const float* __restrict__ in1,
    const float* __restrict__ w, float* __restrict__ out,
    const float* __restrict__ stIn, float* __restrict__ stOut,
    int I, int O, int P, int wio, int zsplit, float invN)
{
  __shared__ float wl[2048];
  __shared__ float bnm[256], bnr[256];
  int tid = threadIdx.x;
  int o0 = blockIdx.y*OT;
  int z  = blockIdx.z;
  int t  = (z >= zsplit) ? 1 : 0;
  int b  = t ? (z - zsplit) : z;
  const float* in = t ? in1 : in0;

  for(int idx=tid; idx<I*OT; idx+=256){
    int i = idx/OT, j = idx - i*OT;
    wl[idx] = wio ? w[(size_t)i*O + o0 + j] : w[(size_t)(o0+j)*I + i];
  }
  if(HASBN){
    for(int i=tid; i<I; i+=256){
      float s  = stIn[((size_t)t*I + i)*2];
      float s2 = stIn[((size_t)t*I + i)*2+1];
      float m  = s*invN;
      bnm[i] = m;
      bnr[i] = rsqrtf(s2*invN - m*m + EPS_BN);
    }
  }
  __syncthreads();

  int p4 = blockIdx.x*256 + tid;            // float4 column index
  const float4* inb = (const float4*)(in + (size_t)b*I*P) + p4;
  int P4 = P >> 2;

  float acc[OT][4];
#pragma unroll
  for(int j=0;j<OT;j++){ acc[j][0]=acc[j][1]=acc[j][2]=acc[j][3]=0.f; }

#pragma unroll 4
  for(int i=0;i<I;i++){
    float4 v = inb[(size_t)i*P4];
    if(HASBN){
      float m = bnm[i], r = bnr[i];
      v.x = fmaxf((v.x-m)*r, 0.f); v.y = fmaxf((v.y-m)*r, 0.f);
      v.z = fmaxf((v.z-m)*r, 0.f); v.w = fmaxf((v.w-m)*r, 0.f);
    }
    const float* wr = &wl[i*OT];
#pragma unroll
    for(int j=0;j<OT;j++){
      float wv = wr[j];
      acc[j][0] = fmaf(wv, v.x, acc[j][0]);
      acc[j][1] = fmaf(wv, v.y, acc[j][1]);
      acc[j][2] = fmaf(wv, v.z, acc[j][2]);
      acc[j][3] = fmaf(wv, v.w, acc[j][3]);
    }
  }

  float4* ob = (float4*)(out + ((size_t)z*O + o0)*P) + p4;
#pragma unroll
  for(int j=0;j<OT;j++){
    float4 vv = {acc[j][0], acc[j][1], acc[j][2], acc[j][3]};
    ob[(size_t)j*P4] = vv;
  }

  if(HASSTATS){
#pragma unroll
    for(int j=0;j<OT;j++){
      float s  = acc[j][0]+acc[j][1]+acc[j][2]+acc[j][3];
      float s2 = acc[j][0]*acc[j][0]+acc[j][1]*acc[j][1]
               + acc[j][2]*acc[j][2]+acc[j][3]*acc[j][3];
      for(int off=32; off>0; off>>=1){
        s  += __shfl_down(s,  off, 64);
        s2 += __shfl_down(s2, off, 64);
      }
      if((tid & 63)==0){
        atomicAdd(&stOut[((size_t)t*O + o0 + j)*2],   s);
        atomicAdd(&stOut[((size_t)t*O + o0 + j)*2+1], s2);
      }
    }
  }
}

// ===========================================================================
// Encoder k=2 s=2 conv, 32ch -> 32ch, 64x64 -> 32x32, w[o,i,2,2] ('ocpq').
// BN+ReLU on load (ST0 sums), stats out (ST1). grid (O/4, Z=16).
// ===========================================================================
__global__ __launch_bounds__(256) void conv2x2s2_bn_kernel(
    const float* __restrict__ in, const float* __restrict__ w,
    float* __restrict__ out, const float* __restrict__ stIn,
    float* __restrict__ stOut, float invN)
{
  __shared__ float wl[512];          // [i*4+j][pq]
  __shared__ float bnm[32], bnr[32];
  int tid = threadIdx.x;
  int o0 = blockIdx.x*4;
  int z  = blockIdx.y;
  int t  = (z >= 8) ? 1 : 0;

  for(int idx=tid; idx<512; idx+=256){
    int pq = idx & 3, r = idx >> 2;  // r = i*4+j
    int i = r >> 2, j = r & 3;
    wl[idx] = w[(((size_t)(o0+j)*32 + i)*4) + pq];
  }
  if(tid < 32){
    float s  = stIn[((size_t)t*32 + tid)*2];
    float s2 = stIn[((size_t)t*32 + tid)*2+1];
    float m  = s*invN;
    bnm[tid] = m;
    bnr[tid] = rsqrtf(s2*invN - m*m + EPS_BN);
  }
  __syncthreads();

  int h  = tid >> 3;          // 0..31 output row
  int wg = tid & 7;           // output col group (4 cols)
  int cb = wg*8;              // input col base (8 cols)

  float acc[4][4];
#pragma unroll
  for(int j=0;j<4;j++) for(int k=0;k<4;k++) acc[j][k]=0.f;

  for(int i=0;i<32;i++){
    const float4* r0 = (const float4*)(in + (((size_t)z*32+i)*64 + 2*h)*64 + cb);
    const float4* r1 = (const float4*)(in + (((size_t)z*32+i)*64 + 2*h+1)*64 + cb);
    float4 a0 = r0[0], a1 = r0[1];
    float4 b0 = r1[0], b1 = r1[1];
    float m = bnm[i], r = bnr[i];
    float t0[8] = {a0.x,a0.y,a0.z,a0.w,a1.x,a1.y,a1.z,a1.w};
    float t1[8] = {b0.x,b0.y,b0.z,b0.w,b1.x,b1.y,b1.z,b1.w};
#pragma unroll
    for(int e=0;e<8;e++){
      t0[e] = fmaxf((t0[e]-m)*r, 0.f);
      t1[e] = fmaxf((t1[e]-m)*r, 0.f);
    }
#pragma unroll
    for(int j=0;j<4;j++){
      const float* wj = &wl[(i*4+j)*4];
#pragma unroll
      for(int k=0;k<4;k++){
        acc[j][k] = fmaf(wj[0], t0[2*k],   acc[j][k]);
        acc[j][k] = fmaf(wj[1], t0[2*k+1], acc[j][k]);
        acc[j][k] = fmaf(wj[2], t1[2*k],   acc[j][k]);
        acc[j][k] = fmaf(wj[3], t1[2*k+1], acc[j][k]);
      }
    }
  }

#pragma unroll
  for(int j=0;j<4;j++){
    float4 vv = {acc[j][0],acc[j][1],acc[j][2],acc[j][3]};
    *(float4*)(out + ((size_t)z*32 + o0+j)*1024 + h*32 + wg*4) = vv;
  }
#pragma unroll
  for(int j=0;j<4;j++){
    float s  = acc[j][0]+acc[j][1]+acc[j][2]+acc[j][3];
    float s2 = acc[j][0]*acc[j][0]+acc[j][1]*acc[j][1]
             + acc[j][2]*acc[j][2]+acc[j][3]*acc[j][3];
    for(int off=32; off>0; off>>=1){
      s  += __shfl_down(s,  off, 64);
      s2 += __shfl_down(s2, off, 64);
    }
    if((tid & 63)==0){
      atomicAdd(&stOut[((size_t)t*32 + o0 + j)*2],   s);
      atomicAdd(&stOut[((size_t)t*32 + o0 + j)*2+1], s2);
    }
  }
}

// ===========================================================================
// ConvTranspose k=2 s=2: in (8,128,32,32) -> out (8,128,64,64), w[i,o,2,2].
// BN+ReLU on load (ST3), stats out (ST4). grid (O/2, B=8). OT=2.
// ===========================================================================
__global__ __launch_bounds__(256) void upsample2x2_bn_kernel(
    const float* __restrict__ in, const float* __restrict__ w,
    float* __restrict__ out, const float* __restrict__ stIn,
    float* __restrict__ stOut, float invN)
{
  __shared__ float wl[1024];          // [i*2+j][pq]
  __shared__ float bnm[128], bnr[128];
  int tid = threadIdx.x;
  int o0 = blockIdx.x*2;
  int b  = blockIdx.y;

  for(int idx=tid; idx<1024; idx+=256){
    int pq = idx & 3, r = idx >> 2;   // r = i*2+j
    int i = r >> 1, j = r & 1;
    wl[idx] = w[((size_t)i*128 + o0+j)*4 + pq];
  }
  if(tid < 128){
    float s  = stIn[(size_t)tid*2];
    float s2 = stIn[(size_t)tid*2+1];
    float m  = s*invN;
    bnm[tid] = m;
    bnr[tid] = rsqrtf(s2*invN - m*m + EPS_BN);
  }
  __syncthreads();

  int h  = tid >> 3;
  int wg = tid & 7;
  int w0 = wg*4;                      // input col base (4 cols)

  float acc[2][16];                   // [j][(p*2+q)*4+k]
#pragma unroll
  for(int j=0;j<2;j++) for(int e=0;e<16;e++) acc[j][e]=0.f;

#pragma unroll 4
  for(int i=0;i<128;i++){
    float4 v = *(const float4*)(in + (((size_t)b*128+i)*1024) + h*32 + w0);
    float m = bnm[i], r = bnr[i];
    float vk[4] = {fmaxf((v.x-m)*r,0.f), fmaxf((v.y-m)*r,0.f),
                   fmaxf((v.z-m)*r,0.f), fmaxf((v.w-m)*r,0.f)};
#pragma unroll
    for(int j=0;j<2;j++){
      const float* wj = &wl[(i*2+j)*4];
#pragma unroll
      for(int pq=0;pq<4;pq++){
#pragma unroll
        for(int k=0;k<4;k++)
          acc[j][pq*4+k] = fmaf(wj[pq], vk[k], acc[j][pq*4+k]);
      }
    }
  }

#pragma unroll
  for(int j=0;j<2;j++){
    float* ob = out + ((size_t)b*128 + o0+j)*4096;
#pragma unroll
    for(int p=0;p<2;p++){
      float4 A = {acc[j][(p*2+0)*4+0], acc[j][(p*2+1)*4+0],
                  acc[j][(p*2+0)*4+1], acc[j][(p*2+1)*4+1]};
      float4 B = {acc[j][(p*2+0)*4+2], acc[j][(p*2+1)*4+2],
                  acc[j][(p*2+0)*4+3], acc[j][(p*2+1)*4+3]};
      *(float4*)(ob + (2*h+p)*64 + 2*w0)     = A;
      *(float4*)(ob + (2*h+p)*64 + 2*w0 + 4) = B;
    }
  }

#pragma unroll
  for(int j=0;j<2;j++){
    float s=0.f, s2=0.f;
#pragma unroll
    for(int e=0;e<16;e++){ s += acc[j][e]; s2 += acc[j][e]*acc[j][e]; }
    for(int off=32; off>0; off>>=1){
      s  += __shfl_down(s,  off, 64);
      s2 += __shfl_down(s2, off, 64);
    }
    if((tid & 63)==0){
      atomicAdd(&stOut[((size_t)(o0+j))*2],   s);
      atomicAdd(&stOut[((size_t)(o0+j))*2+1], s2);
    }
  }
}

// ===========================================================================
// Final BN+ReLU applied in place on d_out from raw sums. float4, grid 8192.
// ===========================================================================
__global__ __launch_bounds__(256) void bn_final_kernel(
    float* __restrict__ x, const float* __restrict__ st, float invN)
{
  int idx4 = blockIdx.x*256 + threadIdx.x;      // float4 index over 2,097,152
  int c = (idx4 >> 10) & 255;
  float s  = st[(size_t)c*2];
  float s2 = st[(size_t)c*2+1];
  float m  = s*invN;
  float r  = rsqrtf(s2*invN - m*m + EPS_BN);
  float4 v = ((float4*)x)[idx4];
  v.x = fmaxf((v.x-m)*r, 0.f); v.y = fmaxf((v.y-m)*r, 0.f);
  v.z = fmaxf((v.z-m)*r, 0.f); v.w = fmaxf((v.w-m)*r, 0.f);
  ((float4*)x)[idx4] = v;
}

// ===========================================================================
// depthwise 3x3, pad 1 (raw in, raw out). w[c,0,3,3]
// ===========================================================================
__global__ __launch_bounds__(256) void dwconv3x3_kernel(
    const float* __restrict__ in, const float* __restrict__ w,
    float* __restrict__ out, int C, int H, int Wd)
{
  int idx = blockIdx.x*256 + threadIdx.x;
  int c = blockIdx.y, b = blockIdx.z;
  if(idx >= H*Wd) return;
  int h = idx / Wd, x = idx - h*Wd;
  const float* inp = in + ((size_t)b*C + c)*H*Wd;
  float acc = 0.f;
#pragma unroll
  for(int p=0;p<3;p++){
    int hh = h + p - 1;
    if((unsigned)hh >= (unsigned)H) continue;
#pragma unroll
    for(int q=0;q<3;q++){
      int wv = x + q - 1;
      if((unsigned)wv >= (unsigned)Wd) continue;
      acc += w[c*9 + p*3 + q] * inp[hh*Wd + wv];
    }
  }
  out[((size_t)b*C + c)*H*Wd + idx] = acc;
}

// ===========================================================================
// full 3x3 conv, pad 1, IC<=64, O = gridDim.y. w[o,i,3,3] (raw in/out)
// ===========================================================================
__global__ __launch_bounds__(256) void conv3x3_kernel(
    const float* __restrict__ in, const float* __restrict__ w,
    float* __restrict__ out, int IC, int H, int Wd)
{
  int o = blockIdx.y, b = blockIdx.z;
  __shared__ float wl[576];
  for(int t=threadIdx.x; t<IC*9; t+=256) wl[t] = w[(size_t)o*IC*9 + t];
  __syncthreads();
  int idx = blockIdx.x*256 + threadIdx.x;
  if(idx >= H*Wd) return;
  int h = idx / Wd, x = idx - h*Wd;
  const float* inb = in + (size_t)b*IC*H*Wd;
  float acc = 0.f;
  for(int i=0;i<IC;i++){
    const float* inp = inb + (size_t)i*H*Wd;
    const float* wp  = wl + i*9;
#pragma unroll
    for(int p=0;p<3;p++){
      int hh = h + p - 1;
      if((unsigned)hh >= (unsigned)H) continue;
      const float* row = inp + hh*Wd;
#pragma unroll
      for(int q=0;q<3;q++){
        int wv = x + q - 1;
        if((unsigned)wv >= (unsigned)Wd) continue;
        acc = fmaf(wp[p*3+q], row[wv], acc);
      }
    }
  }
  out[((size_t)b*gridDim.y + o)*H*Wd + idx] = acc;
}

// ===========================================================================
// F.normalize(dim=-1): 512 rows (b,c), row length 1024, in place.
// ===========================================================================
__global__ __launch_bounds__(256) void l2norm_kernel(float* __restrict__ x, int CB)
{
  int r = blockIdx.x;
  int b = r >> 6, c = r & 63;
  float* p = x + ((size_t)b*CB + c)*1024;
  int tid = threadIdx.x;
  float s = 0.f;
  for(int i=tid;i<1024;i+=256){ float v=p[i]; s += v*v; }
  __shared__ float ls[256];
  ls[tid]=s; __syncthreads();
  for(int st=128; st>0; st>>=1){ if(tid<st) ls[tid]+=ls[tid+st]; __syncthreads(); }
  float scale = 1.f / fmaxf(sqrtf(ls[0]), 1e-12f);
  for(int i=tid;i<1024;i+=256) p[i] *= scale;
}

// ===========================================================================
// Spatial attention pass 1: per row n compute max_m and 1/sum_m exp. 32KB LDS.
// ===========================================================================
__global__ __launch_bounds__(256) void attn_pass1(
    const float* __restrict__ q, const float* __restrict__ kv,
    const float* __restrict__ temp,
    float* __restrict__ mx_out, float* __restrict__ iden_out)
{
  int chunk = blockIdx.x, hh = blockIdx.y, b = blockIdx.z;
  int tid = threadIdx.x;
  __shared__ __align__(16) float kl[8192];          // [m][c], c=0..7
  const float* kb = kv + ((size_t)b*128 + hh*8)*1024;
  for(int t=tid;t<8192;t+=256){ int c=t>>10, m=t&1023; kl[m*8+c]=kb[t]; }
  __syncthreads();
  int n = chunk*256 + tid;
  const float* qp = q + ((size_t)b*64 + hh*8)*1024 + n;
  float qr[8];
#pragma unroll
  for(int c=0;c<8;c++) qr[c]=qp[(size_t)c*1024];
  float th = temp[hh];
  const float4* kl4 = (const float4*)kl;
  float mx = -3.4e38f;
  for(int m=0;m<1024;m++){
    float4 a = kl4[2*m], a2 = kl4[2*m+1];
    float s = qr[0]*a.x+qr[1]*a.y+qr[2]*a.z+qr[3]*a.w
            + qr[4]*a2.x+qr[5]*a2.y+qr[6]*a2.z+qr[7]*a2.w;
    mx = fmaxf(mx, s*th);
  }
  float den = 0.f;
  for(int m=0;m<1024;m++){
    float4 a = kl4[2*m], a2 = kl4[2*m+1];
    float s = qr[0]*a.x+qr[1]*a.y+qr[2]*a.z+qr[3]*a.w
            + qr[4]*a2.x+qr[5]*a2.y+qr[6]*a2.z+qr[7]*a2.w;
    den += __expf(s*th - mx);
  }
  int bh = b*8+hh;
  mx_out[(size_t)bh*1024+n]   = mx;
  iden_out[(size_t)bh*1024+n] = 1.f/den;
}

// ===========================================================================
// Spatial attention pass 2: out[c,m] = sum_n softmax(S)[n,m]*v[c,n].
// ===========================================================================
__global__ __launch_bounds__(256) void attn_pass2(
    const float* __restrict__ q, const float* __restrict__ kv,
    const float* __restrict__ temp,
    const float* __restrict__ mx_in, const float* __restrict__ iden_in,
    float* __restrict__ out)
{
  int chunk = blockIdx.x, hh = blockIdx.y, b = blockIdx.z;
  int tid = threadIdx.x;
  __shared__ __align__(16) float ql[4096];
  __shared__ __align__(16) float vl[4096];
  const float* qb = q  + ((size_t)b*64 + hh*8)*1024;
  const float* vb = kv + ((size_t)b*128 + 64 + hh*8)*1024;
  int bh = b*8+hh;
  int m = chunk*256 + tid;
  const float* kb = kv + ((size_t)b*128 + hh*8)*1024 + m;
  float kr[8];
#pragma unroll
  for(int c=0;c<8;c++) kr[c]=kb[(size_t)c*1024];
  float th = temp[hh];
  const float* mxp = mx_in  + (size_t)bh*1024;
  const float* idp = iden_in + (size_t)bh*1024;
  float acc[8] = {0,0,0,0,0,0,0,0};
  for(int half=0; half<2; half++){
    int n0 = half*512;
    __syncthreads();
    for(int t=tid; t<4096; t+=256){
      int c = t>>9, n = t&511;
      ql[n*8+c] = qb[(size_t)c*1024 + n0 + n];
      vl[n*8+c] = vb[(size_t)c*1024 + n0 + n];
    }
    __syncthreads();
    const float4* ql4 = (const float4*)ql;
    const float4* vl4 = (const float4*)vl;
    for(int n=0;n<512;n++){
      float4 qa = ql4[2*n], qa2 = ql4[2*n+1];
      float s = kr[0]*qa.x+kr[1]*qa.y+kr[2]*qa.z+kr[3]*qa.w
              + kr[4]*qa2.x+kr[5]*qa2.y+kr[6]*qa2.z+kr[7]*qa2.w;
      float pp = __expf(s*th - mxp[n0+n]) * idp[n0+n];
      float4 va = vl4[2*n], va2 = vl4[2*n+1];
      acc[0]+=pp*va.x; acc[1]+=pp*va.y; acc[2]+=pp*va.z; acc[3]+=pp*va.w;
      acc[4]+=pp*va2.x; acc[5]+=pp*va2.y; acc[6]+=pp*va2.z; acc[7]+=pp*va2.w;
    }
  }
  float* ob = out + ((size_t)b*64 + hh*8)*1024 + m;
#pragma unroll
  for(int c=0;c<8;c++) ob[(size_t)c*1024] = acc[c];
}

// ===========================================================================
// Channel attention (8x8 gram per b,head), accumulates (+=) into out.
// ===========================================================================
__global__ __launch_bounds__(256) void attn_channel(
    const float* __restrict__ q, const float* __restrict__ kv,
    const float* __restrict__ temp, float* out)
{
  int hh = blockIdx.x, b = blockIdx.y;
  __shared__ float kl[8192];
  const float* qb = q  + ((size_t)b*64 + hh*8)*1024;
  const float* kb = kv + ((size_t)b*128 + hh*8)*1024;
  const float* vb = kv + ((size_t)b*128 + 64 + hh*8)*1024;
  int tid = threadIdx.x;
  for(int t=tid;t<8192;t+=256) kl[t]=kb[t];
  __syncthreads();
  __shared__ float g[64], a[64];
  if(tid < 64){
    int c = tid >> 3, d = tid & 7;
    float s = 0.f;
    for(int n=0;n<1024;n++) s += qb[(size_t)c*1024+n]*kl[d*1024+n];
    g[tid] = s * temp[hh];
  }
  __syncthreads();
  if(tid < 8){
    float mx = -3.4e38f;
    for(int d=0;d<8;d++) mx = fmaxf(mx, g[tid*8+d]);
    float den = 0.f;
    for(int d=0;d<8;d++){ float e = __expf(g[tid*8+d]-mx); a[tid*8+d]=e; den+=e; }
    float inv = 1.f/den;
    for(int d=0;d<8;d++) a[tid*8+d] *= inv;
  }
  __syncthreads();
  float* ob = out + ((size_t)b*64 + hh*8)*1024;
  for(int n=tid;n<1024;n+=256){
    float vv[8];
#pragma unroll
    for(int d=0;d<8;d++) vv[d] = vb[(size_t)d*1024+n];
#pragma unroll
    for(int c=0;c<8;c++){
      float s = 0.f;
#pragma unroll
      for(int d=0;d<8;d++) s += a[c*8+d]*vv[d];
      ob[(size_t)c*1024+n] += s;
    }
  }
}

// ===========================================================================
extern "C" void kernel_launch(void* const* d_in, const int* in_sizes, int n_in,
                              void* d_out, int out_size, void* d_ws, size_t ws_size,
                              hipStream_t stream)
{
  (void)in_sizes; (void)n_in; (void)out_size; (void)ws_size;
  const float* x      = (const float*)d_in[0];
  const float* y      = (const float*)d_in[1];
  const float* temp   = (const float*)d_in[2];
  const float* enc_w1 = (const float*)d_in[3];
  const float* enc_w2 = (const float*)d_in[4];
  const float* enc_w3 = (const float*)d_in[5];
  const float* kv_w   = (const float*)d_in[6];
  const float* kv_dw_w= (const float*)d_in[7];
  const float* q_w    = (const float*)d_in[8];
  const float* q_dw_w = (const float*)d_in[9];
  const float* proj_w = (const float*)d_in[10];
  const float* dec_w1 = (const float*)d_in[11];
  const float* dec_w2 = (const float*)d_in[12];
  const float* dec_w3 = (const float*)d_in[13];
  float* out = (float*)d_out;

  // Workspace (float offsets). Peak = 6,293,504 floats = 25.2 MB.
  float* W   = (float*)d_ws;
  float* ST  = W;                    // 1536 used (pad to 2048)
  float* ST0 = ST;                   // e1 out stats: 2 x 32 x 2
  float* ST1 = ST + 128;             // e2 out stats: 2 x 32 x 2
  float* ST2 = ST + 256;             // e3 out stats: 2 x 64 x 2
  float* ST3 = ST + 512;             // d1 out stats: 128 x 2
  float* ST4 = ST + 768;             // d2 out stats: 128 x 2
  float* ST5 = ST + 1024;            // d3 out stats: 256 x 2
  float* A    = W + 2048;            // 2,097,152: E1 / {KV1, Qpre} / {ATTN, PROJ, D1}
  float* E1   = A;
  float* KV1  = A;                   // after E2 (E1 dead)
  float* QPre = A + 1048576;
  float* ATTN = A;                   // after attention staging (KV1/QPre dead)
  float* PROJ = A + 524288;
  float* D1   = A + 1048576;
  float* E2   = W + 2099200;         //   524,288
  float* E3   = W + 2623488;         // 1,048,576
  float* KV   = W + 3672064;         // 1,048,576
  float* Q    = W + 4720640;         //   524,288
  float* MX   = W + 5244928;         //    65,536
  float* IDEN = W + 5310464;         //    65,536
  float* D2   = W + 2099200;         // 4,194,304 (overlaps E2..IDEN, all dead)

  const float inv32k = 1.f/32768.f, inv8k = 1.f/8192.f;

  hipMemsetAsync(ST, 0, 2048*sizeof(float), stream);

  // ---- encoder (x and y batched: z in [0,16), zsplit=8) ----
  conv1x1_kernel<8,false,true><<<dim3(4,4,16),256,0,stream>>>(
      x, y, enc_w1, E1, nullptr, ST0, 256, 32, 4096, 0, 8, 0.f);
  conv2x2s2_bn_kernel<<<dim3(8,16),256,0,stream>>>(E1, enc_w2, E2, ST0, ST1, inv32k);
  conv1x1_kernel<4,true,true><<<dim3(1,16,16),256,0,stream>>>(
      E2, E2 + (size_t)8*32*1024, enc_w3, E3, ST1, ST2, 32, 64, 1024, 0, 8, inv8k);

  // ---- kv = dw3x3(1x1(x_enc)); q = conv3x3(1x1(y_enc)) ----
  conv1x1_kernel<4,true,false><<<dim3(1,32,8),256,0,stream>>>(
      E3, E3, kv_w, KV1, ST2, nullptr, 64, 128, 1024, 0, 999, inv8k);
  dwconv3x3_kernel<<<dim3(4,128,8),256,0,stream>>>(KV1, kv_dw_w, KV, 128, 32, 32);
  conv1x1_kernel<4,true,false><<<dim3(1,16,8),256,0,stream>>>(
      E3 + (size_t)8*64*1024, E3, q_w, QPre, ST2 + 128, nullptr, 64, 64, 1024, 0, 999, inv8k);
  conv3x3_kernel<<<dim3(4,64,8),256,0,stream>>>(QPre, q_dw_w, Q, 64, 32, 32);

  // ---- l2 normalize q and k along hw ----
  l2norm_kernel<<<512,256,0,stream>>>(Q, 64);
  l2norm_kernel<<<512,256,0,stream>>>(KV, 128);

  // ---- attention: spatial (2-pass) + channel, accumulated into ATTN ----
  attn_pass1<<<dim3(4,8,8),256,0,stream>>>(Q, KV, temp, MX, IDEN);
  attn_pass2<<<dim3(4,8,8),256,0,stream>>>(Q, KV, temp, MX, IDEN, ATTN);
  attn_channel<<<dim3(8,8),256,0,stream>>>(Q, KV, temp, ATTN);

  // ---- proj (linear => proj(out_s + out_c)) ----
  conv1x1_kernel<4,false,false><<<dim3(1,16,8),256,0,stream>>>(
      ATTN, ATTN, proj_w, PROJ, nullptr, nullptr, 64, 64, 1024, 0, 999, 0.f);

  // ---- decoder ----
  conv1x1_kernel<4,false,true><<<dim3(1,32,8),256,0,stream>>>(
      PROJ, PROJ, dec_w1, D1, nullptr, ST3, 64, 128, 1024, 1, 999, 0.f);
  upsample2x2_bn_kernel<<<dim3(64,8),256,0,stream>>>(D1, dec_w2, D2, ST3, ST4, inv8k);
  conv1x1_kernel<16,true,true><<<dim3(4,16,8),256,0,stream>>>(
      D2, D2, dec_w3, out, ST4, ST5, 128, 256, 4096, 1, 999, inv32k);
  bn_final_kernel<<<8192,256,0,stream>>>(out, ST5, inv32k);
}

// Round 5
// 678.134 us; speedup vs baseline: 2.1264x; 1.3277x over previous
//
#include <hip/hip_runtime.h>
#include <hip/hip_bf16.h>

#define EPS_BN 1e-5f

// ===========================================================================
// Tiled 1x1 conv (GEMM): out[z,o,p] = sum_i w(o,i) * in[z,i,p]
//  - 256 threads, each 4 consecutive cols (float4) x OT outputs
//  - grid: (P/1024, O/OT, Z)
//  - 8-deep explicit load pipeline (8 global_load_dwordx4 in flight/thread)
//  - weights in LDS; optional BN+ReLU on load (raw sums in stIn);
//    optional per-channel sum/sumsq to stOut via wave-reduce + atomics.
//  - z >= zsplit reads in1; tensor index t selects stats bank.
// ===========================================================================
template<int OT, bool HASBN, bool HASSTATS>
__global__ __launch_bounds__(256) void conv1x1_kernel(
    const float* __restrict__ in0, const float* __restrict__ in1,
    const float* __restrict__ w, float* __restrict__ out,
    const float* __restrict__ stIn, float* __restrict__ stOut,
    int I, int O, int P, int wio, int zsplit, float invN)
{
  __shared__ float wl[2048];
  __shared__ float bnm[256], bnr[256];
  int tid = threadIdx.x;
  int o0 = blockIdx.y*OT;
  int z  = blockIdx.z;
  int t  = (z >= zsplit) ? 1 : 0;
  int b  = t ? (z - zsplit) : z;
  const float* in = t ? in1 : in0;

  for(int idx=tid; idx<I*OT; idx+=256){
    int i = idx/OT, j = idx - i*OT;
    wl[idx] = wio ? w[(size_t)i*O + o0 + j] : w[(size_t)(o0+j)*I + i];
  }
  if(HASBN){
    for(int i=tid; i<I; i+=256){
      float s  = stIn[((size_t)t*I + i)*2];
      float s2 = stIn[((size_t)t*I + i)*2+1];
      float m  = s*invN;
      bnm[i] = m;
      bnr[i] = rsqrtf(s2*invN - m*m + EPS_BN);
    }
  }
  __syncthreads();

  int p4 = blockIdx.x*256 + tid;            // float4 column index
  const float4* inb = (const float4*)(in + (size_t)b*I*P) + p4;
  int P4 = P >> 2;

  float acc[OT][4];
#pragma unroll
  for(int j=0;j<OT;j++){ acc[j][0]=acc[j][1]=acc[j][2]=acc[j][3]=0.f; }

  float4 vb[8];
  for(int i0=0;i0<I;i0+=8){
#pragma unroll
    for(int u=0;u<8;u++) vb[u] = inb[(size_t)(i0+u)*P4];
#pragma unroll
    for(int u=0;u<8;u++){
      float4 v = vb[u];
      if(HASBN){
        float m = bnm[i0+u], r = bnr[i0+u];
        v.x = fmaxf((v.x-m)*r, 0.f); v.y = fmaxf((v.y-m)*r, 0.f);
        v.z = fmaxf((v.z-m)*r, 0.f); v.w = fmaxf((v.w-m)*r, 0.f);
      }
      const float* wr = &wl[(i0+u)*OT];
#pragma unroll
      for(int j=0;j<OT;j++){
        float wv = wr[j];
        acc[j][0] = fmaf(wv, v.x, acc[j][0]);
        acc[j][1] = fmaf(wv, v.y, acc[j][1]);
        acc[j][2] = fmaf(wv, v.z, acc[j][2]);
        acc[j][3] = fmaf(wv, v.w, acc[j][3]);
      }
    }
  }

  float4* ob = (float4*)(out + ((size_t)z*O + o0)*P) + p4;
#pragma unroll
  for(int j=0;j<OT;j++){
    float4 vv = {acc[j][0], acc[j][1], acc[j][2], acc[j][3]};
    ob[(size_t)j*P4] = vv;
  }

  if(HASSTATS){
#pragma unroll
    for(int j=0;j<OT;j++){
      float s  = acc[j][0]+acc[j][1]+acc[j][2]+acc[j][3];
      float s2 = acc[j][0]*acc[j][0]+acc[j][1]*acc[j][1]
               + acc[j][2]*acc[j][2]+acc[j][3]*acc[j][3];
      for(int off=32; off>0; off>>=1){
        s  += __shfl_down(s,  off, 64);
        s2 += __shfl_down(s2, off, 64);
      }
      if((tid & 63)==0){
        atomicAdd(&stOut[((size_t)t*O + o0 + j)*2],   s);
        atomicAdd(&stOut[((size_t)t*O + o0 + j)*2+1], s2);
      }
    }
  }
}

// ===========================================================================
// Encoder k=2 s=2 conv, 32ch -> 32ch, 64x64 -> 32x32, w[o,i,2,2].
// BN+ReLU on load (ST0), stats out (ST1). grid (O/4, Z=16).
// ===========================================================================
__global__ __launch_bounds__(256) void conv2x2s2_bn_kernel(
    const float* __restrict__ in, const float* __restrict__ w,
    float* __restrict__ out, const float* __restrict__ stIn,
    float* __restrict__ stOut, float invN)
{
  __shared__ float wl[512];          // [i*4+j][pq]
  __shared__ float bnm[32], bnr[32];
  int tid = threadIdx.x;
  int o0 = blockIdx.x*4;
  int z  = blockIdx.y;
  int t  = (z >= 8) ? 1 : 0;

  for(int idx=tid; idx<512; idx+=256){
    int pq = idx & 3, r = idx >> 2;  // r = i*4+j
    int i = r >> 2, j = r & 3;
    wl[idx] = w[(((size_t)(o0+j)*32 + i)*4) + pq];
  }
  if(tid < 32){
    float s  = stIn[((size_t)t*32 + tid)*2];
    float s2 = stIn[((size_t)t*32 + tid)*2+1];
    float m  = s*invN;
    bnm[tid] = m;
    bnr[tid] = rsqrtf(s2*invN - m*m + EPS_BN);
  }
  __syncthreads();

  int h  = tid >> 3;          // output row
  int wg = tid & 7;           // output col group (4 cols)
  int cb = wg*8;              // input col base (8 cols)

  float acc[4][4];
#pragma unroll
  for(int j=0;j<4;j++) for(int k=0;k<4;k++) acc[j][k]=0.f;

  float4 pre[8];              // 4-i prefetch x 2 rows... (2 loads per i, 4 i)
  for(int i0=0;i0<32;i0+=4){
#pragma unroll
    for(int u=0;u<4;u++){
      pre[2*u]   = *(const float4*)(in + (((size_t)z*32+i0+u)*64 + 2*h)*64 + cb);
      pre[2*u+1] = *(const float4*)(in + (((size_t)z*32+i0+u)*64 + 2*h)*64 + cb + 4);
    }
#pragma unroll
    for(int u=0;u<4;u++){
      int i = i0+u;
      const float4* r1p = (const float4*)(in + (((size_t)z*32+i)*64 + 2*h+1)*64 + cb);
      float4 a0 = pre[2*u], a1 = pre[2*u+1];
      float4 b0 = r1p[0], b1 = r1p[1];
      float m = bnm[i], r = bnr[i];
      float t0[8] = {a0.x,a0.y,a0.z,a0.w,a1.x,a1.y,a1.z,a1.w};
      float t1[8] = {b0.x,b0.y,b0.z,b0.w,b1.x,b1.y,b1.z,b1.w};
#pragma unroll
      for(int e=0;e<8;e++){
        t0[e] = fmaxf((t0[e]-m)*r, 0.f);
        t1[e] = fmaxf((t1[e]-m)*r, 0.f);
      }
#pragma unroll
      for(int j=0;j<4;j++){
        const float* wj = &wl[(i*4+j)*4];
#pragma unroll
        for(int k=0;k<4;k++){
          acc[j][k] = fmaf(wj[0], t0[2*k],   acc[j][k]);
          acc[j][k] = fmaf(wj[1], t0[2*k+1], acc[j][k]);
          acc[j][k] = fmaf(wj[2], t1[2*k],   acc[j][k]);
          acc[j][k] = fmaf(wj[3], t1[2*k+1], acc[j][k]);
        }
      }
    }
  }

#pragma unroll
  for(int j=0;j<4;j++){
    float4 vv = {acc[j][0],acc[j][1],acc[j][2],acc[j][3]};
    *(float4*)(out + ((size_t)z*32 + o0+j)*1024 + h*32 + wg*4) = vv;
  }
#pragma unroll
  for(int j=0;j<4;j++){
    float s  = acc[j][0]+acc[j][1]+acc[j][2]+acc[j][3];
    float s2 = acc[j][0]*acc[j][0]+acc[j][1]*acc[j][1]
             + acc[j][2]*acc[j][2]+acc[j][3]*acc[j][3];
    for(int off=32; off>0; off>>=1){
      s  += __shfl_down(s,  off, 64);
      s2 += __shfl_down(s2, off, 64);
    }
    if((tid & 63)==0){
      atomicAdd(&stOut[((size_t)t*32 + o0 + j)*2],   s);
      atomicAdd(&stOut[((size_t)t*32 + o0 + j)*2+1], s2);
    }
  }
}

// ===========================================================================
// ConvTranspose k=2 s=2: (8,128,32,32) -> (8,128,64,64), w[i,o,2,2].
// BN+ReLU on load (ST3), stats out (ST4). grid (O/2, B=8). 8-deep prefetch.
// ===========================================================================
__global__ __launch_bounds__(256) void upsample2x2_bn_kernel(
    const float* __restrict__ in, const float* __restrict__ w,
    float* __restrict__ out, const float* __restrict__ stIn,
    float* __restrict__ stOut, float invN)
{
  __shared__ float wl[1024];          // [i*2+j][pq]
  __shared__ float bnm[128], bnr[128];
  int tid = threadIdx.x;
  int o0 = blockIdx.x*2;
  int b  = blockIdx.y;

  for(int idx=tid; idx<1024; idx+=256){
    int pq = idx & 3, r = idx >> 2;   // r = i*2+j
    int i = r >> 1, j = r & 1;
    wl[idx] = w[((size_t)i*128 + o0+j)*4 + pq];
  }
  if(tid < 128){
    float s  = stIn[(size_t)tid*2];
    float s2 = stIn[(size_t)tid*2+1];
    float m  = s*invN;
    bnm[tid] = m;
    bnr[tid] = rsqrtf(s2*invN - m*m + EPS_BN);
  }
  __syncthreads();

  int h  = tid >> 3;
  int wg = tid & 7;
  int w0 = wg*4;

  float acc[2][16];
#pragma unroll
  for(int j=0;j<2;j++) for(int e=0;e<16;e++) acc[j][e]=0.f;

  float4 vb4[8];
  for(int i0=0;i0<128;i0+=8){
#pragma unroll
    for(int u=0;u<8;u++)
      vb4[u] = *(const float4*)(in + (((size_t)b*128+i0+u)*1024) + h*32 + w0);
#pragma unroll
    for(int u=0;u<8;u++){
      int i = i0+u;
      float4 v = vb4[u];
      float m = bnm[i], r = bnr[i];
      float vk[4] = {fmaxf((v.x-m)*r,0.f), fmaxf((v.y-m)*r,0.f),
                     fmaxf((v.z-m)*r,0.f), fmaxf((v.w-m)*r,0.f)};
#pragma unroll
      for(int j=0;j<2;j++){
        const float* wj = &wl[(i*2+j)*4];
#pragma unroll
        for(int pq=0;pq<4;pq++){
#pragma unroll
          for(int k=0;k<4;k++)
            acc[j][pq*4+k] = fmaf(wj[pq], vk[k], acc[j][pq*4+k]);
        }
      }
    }
  }

#pragma unroll
  for(int j=0;j<2;j++){
    float* ob = out + ((size_t)b*128 + o0+j)*4096;
#pragma unroll
    for(int p=0;p<2;p++){
      float4 A = {acc[j][(p*2+0)*4+0], acc[j][(p*2+1)*4+0],
                  acc[j][(p*2+0)*4+1], acc[j][(p*2+1)*4+1]};
      float4 B = {acc[j][(p*2+0)*4+2], acc[j][(p*2+1)*4+2],
                  acc[j][(p*2+0)*4+3], acc[j][(p*2+1)*4+3]};
      *(float4*)(ob + (2*h+p)*64 + 2*w0)     = A;
      *(float4*)(ob + (2*h+p)*64 + 2*w0 + 4) = B;
    }
  }

#pragma unroll
  for(int j=0;j<2;j++){
    float s=0.f, s2=0.f;
#pragma unroll
    for(int e=0;e<16;e++){ s += acc[j][e]; s2 += acc[j][e]*acc[j][e]; }
    for(int off=32; off>0; off>>=1){
      s  += __shfl_down(s,  off, 64);
      s2 += __shfl_down(s2, off, 64);
    }
    if((tid & 63)==0){
      atomicAdd(&stOut[((size_t)(o0+j))*2],   s);
      atomicAdd(&stOut[((size_t)(o0+j))*2+1], s2);
    }
  }
}

// ===========================================================================
// Final BN+ReLU in place on d_out from raw sums. float4, grid 8192.
// ===========================================================================
__global__ __launch_bounds__(256) void bn_final_kernel(
    float* __restrict__ x, const float* __restrict__ st, float invN)
{
  int idx4 = blockIdx.x*256 + threadIdx.x;
  int c = (idx4 >> 10) & 255;
  float s  = st[(size_t)c*2];
  float s2 = st[(size_t)c*2+1];
  float m  = s*invN;
  float r  = rsqrtf(s2*invN - m*m + EPS_BN);
  float4 v = ((float4*)x)[idx4];
  v.x = fmaxf((v.x-m)*r, 0.f); v.y = fmaxf((v.y-m)*r, 0.f);
  v.z = fmaxf((v.z-m)*r, 0.f); v.w = fmaxf((v.w-m)*r, 0.f);
  ((float4*)x)[idx4] = v;
}

// ===========================================================================
// depthwise 3x3, pad 1 (raw in/out). w[c,0,3,3]
// ===========================================================================
__global__ __launch_bounds__(256) void dwconv3x3_kernel(
    const float* __restrict__ in, const float* __restrict__ w,
    float* __restrict__ out, int C, int H, int Wd)
{
  int idx = blockIdx.x*256 + threadIdx.x;
  int c = blockIdx.y, b = blockIdx.z;
  if(idx >= H*Wd) return;
  int h = idx / Wd, x = idx - h*Wd;
  const float* inp = in + ((size_t)b*C + c)*H*Wd;
  float acc = 0.f;
#pragma unroll
  for(int p=0;p<3;p++){
    int hh = h + p - 1;
    if((unsigned)hh >= (unsigned)H) continue;
#pragma unroll
    for(int q=0;q<3;q++){
      int wv = x + q - 1;
      if((unsigned)wv >= (unsigned)Wd) continue;
      acc += w[c*9 + p*3 + q] * inp[hh*Wd + wv];
    }
  }
  out[((size_t)b*C + c)*H*Wd + idx] = acc;
}

// ===========================================================================
// full 3x3 conv, pad 1, IC<=64, O = gridDim.y. w[o,i,3,3]
// ===========================================================================
__global__ __launch_bounds__(256) void conv3x3_kernel(
    const float* __restrict__ in, const float* __restrict__ w,
    float* __restrict__ out, int IC, int H, int Wd)
{
  int o = blockIdx.y, b = blockIdx.z;
  __shared__ float wl[576];
  for(int t=threadIdx.x; t<IC*9; t+=256) wl[t] = w[(size_t)o*IC*9 + t];
  __syncthreads();
  int idx = blockIdx.x*256 + threadIdx.x;
  if(idx >= H*Wd) return;
  int h = idx / Wd, x = idx - h*Wd;
  const float* inb = in + (size_t)b*IC*H*Wd;
  float acc = 0.f;
  for(int i=0;i<IC;i++){
    const float* inp = inb + (size_t)i*H*Wd;
    const float* wp  = wl + i*9;
#pragma unroll
    for(int p=0;p<3;p++){
      int hh = h + p - 1;
      if((unsigned)hh >= (unsigned)H) continue;
      const float* row = inp + hh*Wd;
#pragma unroll
      for(int q=0;q<3;q++){
        int wv = x + q - 1;
        if((unsigned)wv >= (unsigned)Wd) continue;
        acc = fmaf(wp[p*3+q], row[wv], acc);
      }
    }
  }
  out[((size_t)b*gridDim.y + o)*H*Wd + idx] = acc;
}

// ===========================================================================
// F.normalize(dim=-1) for q (512 rows) and k (512 rows), grid 1024.
// Row = 1024 floats = 256 float4 (one per thread).
// ===========================================================================
__global__ __launch_bounds__(256) void l2norm_kernel(
    float* __restrict__ q, float* __restrict__ kv)
{
  int r = blockIdx.x;
  float* p;
  if(r < 512){ int b=r>>6, c=r&63; p = q + ((size_t)b*64+c)*1024; }
  else { int rr=r-512; int b=rr>>6, c=rr&63; p = kv + ((size_t)b*128+c)*1024; }
  int tid = threadIdx.x;
  float4 v = ((float4*)p)[tid];
  float s = v.x*v.x + v.y*v.y + v.z*v.z + v.w*v.w;
  __shared__ float ls[256];
  ls[tid]=s; __syncthreads();
  for(int st=128; st>0; st>>=1){ if(tid<st) ls[tid]+=ls[tid+st]; __syncthreads(); }
  float scale = 1.f / fmaxf(sqrtf(ls[0]), 1e-12f);
  v.x*=scale; v.y*=scale; v.z*=scale; v.w*=scale;
  ((float4*)p)[tid] = v;
}

// ===========================================================================
// Spatial attention pass 1: per row n compute 1/sum_m exp(s*t - |t|).
// Valid stable shift: |q.k| <= 1 after l2norm, so max score <= |t|.
// q: (b,64,1024); kv: (b,128,1024), k = channels 0..63. grid (4,8,8).
// ===========================================================================
__global__ __launch_bounds__(256) void attn_pass1(
    const float* __restrict__ q, const float* __restrict__ kv,
    const float* __restrict__ temp, float* __restrict__ iden_out)
{
  int chunk = blockIdx.x, hh = blockIdx.y, b = blockIdx.z;
  int tid = threadIdx.x;
  __shared__ __align__(16) float kl[8192];          // [m][c], c=0..7
  const float* kb = kv + ((size_t)b*128 + hh*8)*1024;
  for(int t=tid;t<8192;t+=256){ int c=t>>10, m=t&1023; kl[m*8+c]=kb[t]; }
  __syncthreads();
  int n = chunk*256 + tid;
  const float* qp = q + ((size_t)b*64 + hh*8)*1024 + n;
  float qr[8];
#pragma unroll
  for(int c=0;c<8;c++) qr[c]=qp[(size_t)c*1024];
  float th = temp[hh];
  float mxb = fabsf(th);
  const float4* kl4 = (const float4*)kl;
  float den = 0.f;
  for(int m=0;m<1024;m++){
    float4 a = kl4[2*m], a2 = kl4[2*m+1];
    float s = qr[0]*a.x+qr[1]*a.y+qr[2]*a.z+qr[3]*a.w
            + qr[4]*a2.x+qr[5]*a2.y+qr[6]*a2.z+qr[7]*a2.w;
    den += __expf(s*th - mxb);
  }
  int bh = b*8+hh;
  iden_out[(size_t)bh*1024+n] = 1.f/den;
}

// ===========================================================================
// Spatial attention pass 2: out[c,m] = sum_n softmax(S)[n,m]*v[c,n].
// ===========================================================================
__global__ __launch_bounds__(256) void attn_pass2(
    const float* __restrict__ q, const float* __restrict__ kv,
    const float* __restrict__ temp, const float* __restrict__ iden_in,
    float* __restrict__ out)
{
  int chunk = blockIdx.x, hh = blockIdx.y, b = blockIdx.z;
  int tid = threadIdx.x;
  __shared__ __align__(16) float ql[4096];
  __shared__ __align__(16) float vl[4096];
  const float* qb = q  + ((size_t)b*64 + hh*8)*1024;
  const float* vb = kv + ((size_t)b*128 + 64 + hh*8)*1024;
  int bh = b*8+hh;
  int m = chunk*256 + tid;
  const float* kb = kv + ((size_t)b*128 + hh*8)*1024 + m;
  float kr[8];
#pragma unroll
  for(int c=0;c<8;c++) kr[c]=kb[(size_t)c*1024];
  float th = temp[hh];
  float mxb = fabsf(th);
  const float* idp = iden_in + (size_t)bh*1024;
  float acc[8] = {0,0,0,0,0,0,0,0};
  for(int half=0; half<2; half++){
    int n0 = half*512;
    __syncthreads();
    for(int t=tid; t<4096; t+=256){
      int c = t>>9, n = t&511;
      ql[n*8+c] = qb[(size_t)c*1024 + n0 + n];
      vl[n*8+c] = vb[(size_t)c*1024 + n0 + n];
    }
    __syncthreads();
    const float4* ql4 = (const float4*)ql;
    const float4* vl4 = (const float4*)vl;
    for(int n=0;n<512;n++){
      float4 qa = ql4[2*n], qa2 = ql4[2*n+1];
      float s = kr[0]*qa.x+kr[1]*qa.y+kr[2]*qa.z+kr[3]*qa.w
              + kr[4]*qa2.x+kr[5]*qa2.y+kr[6]*qa2.z+kr[7]*qa2.w;
      float pp = __expf(s*th - mxb) * idp[n0+n];
      float4 va = vl4[2*n], va2 = vl4[2*n+1];
      acc[0]+=pp*va.x; acc[1]+=pp*va.y; acc[2]+=pp*va.z; acc[3]+=pp*va.w;
      acc[4]+=pp*va2.x; acc[5]+=pp*va2.y; acc[6]+=pp*va2.z; acc[7]+=pp*va2.w;
    }
  }
  float* ob = out + ((size_t)b*64 + hh*8)*1024 + m;
#pragma unroll
  for(int c=0;c<8;c++) ob[(size_t)c*1024] = acc[c];
}

// ===========================================================================
// Channel attention (8x8 gram per b,head), accumulates (+=) into out. grid (8,8)
// Gram parallelized: 64 (c,d) pairs x 4 segment-threads.
// ===========================================================================
__global__ __launch_bounds__(256) void attn_channel(
    const float* __restrict__ q, const float* __restrict__ kv,
    const float* __restrict__ temp, float* out)
{
  int hh = blockIdx.x, b = blockIdx.y;
  __shared__ float kl[8192];
  const float* qb = q  + ((size_t)b*64 + hh*8)*1024;
  const float* kb = kv + ((size_t)b*128 + hh*8)*1024;
  const float* vb = kv + ((size_t)b*128 + 64 + hh*8)*1024;
  int tid = threadIdx.x;
  for(int t=tid;t<8192;t+=256) kl[t]=kb[t];
  __syncthreads();
  __shared__ float part[256];
  __shared__ float a[64];
  {
    int pair = tid >> 2, seg = tid & 3;
    int c = pair >> 3, d = pair & 7;
    const float* qrow = qb + (size_t)c*1024 + seg*256;
    const float* krow = kl + d*1024 + seg*256;
    float s = 0.f;
#pragma unroll 4
    for(int n=0;n<256;n++) s += qrow[n]*krow[n];
    part[tid] = s;
  }
  __syncthreads();
  if(tid < 64){
    float g = part[tid*4]+part[tid*4+1]+part[tid*4+2]+part[tid*4+3];
    part[tid] = g * temp[hh];   // reuse part[0..63] as gram
  }
  __syncthreads();
  if(tid < 8){
    float mx = -3.4e38f;
    for(int d=0;d<8;d++) mx = fmaxf(mx, part[tid*8+d]);
    float den = 0.f;
    float e[8];
    for(int d=0;d<8;d++){ e[d] = __expf(part[tid*8+d]-mx); den+=e[d]; }
    float inv = 1.f/den;
    for(int d=0;d<8;d++) a[tid*8+d] = e[d]*inv;
  }
  __syncthreads();
  float* ob = out + ((size_t)b*64 + hh*8)*1024;
  for(int n=tid;n<1024;n+=256){
    float vv[8];
#pragma unroll
    for(int d=0;d<8;d++) vv[d] = vb[(size_t)d*1024+n];
#pragma unroll
    for(int c=0;c<8;c++){
      float s = 0.f;
#pragma unroll
      for(int d=0;d<8;d++) s += a[c*8+d]*vv[d];
      ob[(size_t)c*1024+n] += s;
    }
  }
}

// ===========================================================================
extern "C" void kernel_launch(void* const* d_in, const int* in_sizes, int n_in,
                              void* d_out, int out_size, void* d_ws, size_t ws_size,
                              hipStream_t stream)
{
  (void)in_sizes; (void)n_in; (void)out_size; (void)ws_size;
  const float* x      = (const float*)d_in[0];
  const float* y      = (const float*)d_in[1];
  const float* temp   = (const float*)d_in[2];
  const float* enc_w1 = (const float*)d_in[3];
  const float* enc_w2 = (const float*)d_in[4];
  const float* enc_w3 = (const float*)d_in[5];
  const float* kv_w   = (const float*)d_in[6];
  const float* kv_dw_w= (const float*)d_in[7];
  const float* q_w    = (const float*)d_in[8];
  const float* q_dw_w = (const float*)d_in[9];
  const float* proj_w = (const float*)d_in[10];
  const float* dec_w1 = (const float*)d_in[11];
  const float* dec_w2 = (const float*)d_in[12];
  const float* dec_w3 = (const float*)d_in[13];
  float* out = (float*)d_out;

  // Workspace (float offsets). Peak ~25.2 MB.
  float* W   = (float*)d_ws;
  float* ST  = W;                    // 2048
  float* ST0 = ST;                   // e1 stats: 2 x 32 x 2
  float* ST1 = ST + 128;             // e2 stats: 2 x 32 x 2
  float* ST2 = ST + 256;             // e3 stats: 2 x 64 x 2
  float* ST3 = ST + 512;             // d1 stats: 128 x 2
  float* ST4 = ST + 768;             // d2 stats: 128 x 2
  float* ST5 = ST + 1024;            // d3 stats: 256 x 2
  float* A    = W + 2048;            // 2,097,152 region, multiply reused
  float* E1   = A;
  float* KV1  = A;                   // after E2 (E1 dead)
  float* QPre = A + 1048576;
  float* ATTN = A;                   // after attention staging
  float* PROJ = A + 524288;
  float* D1   = A + 1048576;
  float* E2   = W + 2099200;         //   524,288
  float* E3   = W + 2623488;         // 1,048,576
  float* KV   = W + 3672064;         // 1,048,576
  float* Q    = W + 4720640;         //   524,288
  float* IDEN = W + 5244928;         //    65,536
  float* D2   = W + 2099200;         // 4,194,304 (overlaps E2..IDEN, all dead)

  const float inv32k = 1.f/32768.f, inv8k = 1.f/8192.f;

  hipMemsetAsync(ST, 0, 2048*sizeof(float), stream);

  // ---- encoder (x and y batched: z in [0,16), zsplit=8) ----
  conv1x1_kernel<4,false,true><<<dim3(4,8,16),256,0,stream>>>(
      x, y, enc_w1, E1, nullptr, ST0, 256, 32, 4096, 0, 8, 0.f);
  conv2x2s2_bn_kernel<<<dim3(8,16),256,0,stream>>>(E1, enc_w2, E2, ST0, ST1, inv32k);
  conv1x1_kernel<2,true,true><<<dim3(1,32,16),256,0,stream>>>(
      E2, E2 + (size_t)8*32*1024, enc_w3, E3, ST1, ST2, 32, 64, 1024, 0, 8, inv8k);

  // ---- kv = dw3x3(1x1(x_enc)); q = conv3x3(1x1(y_enc)) ----
  conv1x1_kernel<4,true,false><<<dim3(1,32,8),256,0,stream>>>(
      E3, E3, kv_w, KV1, ST2, nullptr, 64, 128, 1024, 0, 999, inv8k);
  dwconv3x3_kernel<<<dim3(4,128,8),256,0,stream>>>(KV1, kv_dw_w, KV, 128, 32, 32);
  conv1x1_kernel<2,true,false><<<dim3(1,32,8),256,0,stream>>>(
      E3 + (size_t)8*64*1024, E3, q_w, QPre, ST2 + 128, nullptr, 64, 64, 1024, 0, 999, inv8k);
  conv3x3_kernel<<<dim3(4,64,8),256,0,stream>>>(QPre, q_dw_w, Q, 64, 32, 32);

  // ---- l2 normalize q and k along hw (1024 rows in one launch) ----
  l2norm_kernel<<<1024,256,0,stream>>>(Q, KV);

  // ---- attention: spatial (2-pass, |t| shift) + channel, into ATTN ----
  attn_pass1<<<dim3(4,8,8),256,0,stream>>>(Q, KV, temp, IDEN);
  attn_pass2<<<dim3(4,8,8),256,0,stream>>>(Q, KV, temp, IDEN, ATTN);
  attn_channel<<<dim3(8,8),256,0,stream>>>(Q, KV, temp, ATTN);

  // ---- proj (linear => proj(out_s + out_c)) ----
  conv1x1_kernel<2,false,false><<<dim3(1,32,8),256,0,stream>>>(
      ATTN, ATTN, proj_w, PROJ, nullptr, nullptr, 64, 64, 1024, 0, 999, 0.f);

  // ---- decoder ----
  conv1x1_kernel<4,false,true><<<dim3(1,32,8),256,0,stream>>>(
      PROJ, PROJ, dec_w1, D1, nullptr, ST3, 64, 128, 1024, 1, 999, 0.f);
  upsample2x2_bn_kernel<<<dim3(64,8),256,0,stream>>>(D1, dec_w2, D2, ST3, ST4, inv8k);
  conv1x1_kernel<8,true,true><<<dim3(4,32,8),256,0,stream>>>(
      D2, D2, dec_w3, out, ST4, ST5, 128, 256, 4096, 1, 999, inv32k);
  bn_final_kernel<<<8192,256,0,stream>>>(out, ST5, inv32k);
}

// Round 6
// 637.500 us; speedup vs baseline: 2.2620x; 1.0637x over previous
//
#include <hip/hip_runtime.h>
#include <hip/hip_bf16.h>

#define EPS_BN 1e-5f

// ===========================================================================
// enc1: LDS-tiled GEMM  out[z,o,p] = sum_i w[o,i]*in[z,i,p]
// I=256, O=32, P=4096, z in [0,16) (x then y). Tile: 128 cols x 32 outs.
// K staged in 8 chunks of 32 ch (16KB il + 4KB wt). Re-read factor 1.
// grid (32 col-tiles, 16 z), 256 thr: cg=tid&31 (float4 col), og=tid>>5 (4 o).
// ===========================================================================
__global__ __launch_bounds__(256) void conv1x1_enc1_kernel(
    const float* __restrict__ in0, const float* __restrict__ in1,
    const float* __restrict__ w, float* __restrict__ out,
    float* __restrict__ stOut)
{
  __shared__ float il[32*128];     // [ch][col] 16 KB
  __shared__ float wt[32*32];      // [ch][o]    4 KB
  int tid  = threadIdx.x;
  int tile = blockIdx.x;
  int z    = blockIdx.y;
  int t    = z >> 3;
  const float* in  = t ? in1 : in0;
  const float* inb = in + ((size_t)(z&7))*256*4096 + tile*128;
  int cg = tid & 31;
  int og = tid >> 5;

  float acc[4][4];
#pragma unroll
  for(int j=0;j<4;j++){ acc[j][0]=acc[j][1]=acc[j][2]=acc[j][3]=0.f; }

  for(int k0=0; k0<256; k0+=32){
    __syncthreads();
#pragma unroll
    for(int u=0;u<4;u++){
      int fid = tid + u*256;               // 0..1023 float4 slots
      int ch = fid >> 5, c4 = fid & 31;
      ((float4*)il)[fid] = *(const float4*)(inb + (size_t)(k0+ch)*4096 + c4*4);
    }
#pragma unroll
    for(int u=0;u<4;u++){
      int idx = tid + u*256;               // 0..1023
      int o = idx >> 5, ch = idx & 31;
      wt[ch*32 + o] = w[(size_t)o*256 + k0 + ch];
    }
    __syncthreads();
#pragma unroll 8
    for(int ch=0; ch<32; ch++){
      float4 v  = ((float4*)il)[ch*32 + cg];
      float4 wv = ((float4*)wt)[ch*8 + og];
      acc[0][0]=fmaf(wv.x,v.x,acc[0][0]); acc[0][1]=fmaf(wv.x,v.y,acc[0][1]);
      acc[0][2]=fmaf(wv.x,v.z,acc[0][2]); acc[0][3]=fmaf(wv.x,v.w,acc[0][3]);
      acc[1][0]=fmaf(wv.y,v.x,acc[1][0]); acc[1][1]=fmaf(wv.y,v.y,acc[1][1]);
      acc[1][2]=fmaf(wv.y,v.z,acc[1][2]); acc[1][3]=fmaf(wv.y,v.w,acc[1][3]);
      acc[2][0]=fmaf(wv.z,v.x,acc[2][0]); acc[2][1]=fmaf(wv.z,v.y,acc[2][1]);
      acc[2][2]=fmaf(wv.z,v.z,acc[2][2]); acc[2][3]=fmaf(wv.z,v.w,acc[2][3]);
      acc[3][0]=fmaf(wv.w,v.x,acc[3][0]); acc[3][1]=fmaf(wv.w,v.y,acc[3][1]);
      acc[3][2]=fmaf(wv.w,v.z,acc[3][2]); acc[3][3]=fmaf(wv.w,v.w,acc[3][3]);
    }
  }

  float* ob = out + ((size_t)z*32 + og*4)*4096 + tile*128 + cg*4;
#pragma unroll
  for(int j=0;j<4;j++){
    float4 vv = {acc[j][0],acc[j][1],acc[j][2],acc[j][3]};
    *(float4*)(ob + (size_t)j*4096) = vv;
  }
  // stats: lanes 0..31 of each half-wave share og (same 4 outs)
#pragma unroll
  for(int j=0;j<4;j++){
    float s  = acc[j][0]+acc[j][1]+acc[j][2]+acc[j][3];
    float s2 = acc[j][0]*acc[j][0]+acc[j][1]*acc[j][1]
             + acc[j][2]*acc[j][2]+acc[j][3]*acc[j][3];
    for(int off=16; off>0; off>>=1){
      s  += __shfl_down(s,  off, 64);
      s2 += __shfl_down(s2, off, 64);
    }
    if((tid & 31)==0){
      atomicAdd(&stOut[((size_t)t*32 + og*4 + j)*2],   s);
      atomicAdd(&stOut[((size_t)t*32 + og*4 + j)*2+1], s2);
    }
  }
}

// ===========================================================================
// Generic tiled 1x1 conv (8-deep pipelined loads), as round 5.
// ===========================================================================
template<int OT, bool HASBN, bool HASSTATS>
__global__ __launch_bounds__(256) void conv1x1_kernel(
    const float* __restrict__ in0, const float* __restrict__ in1,
    const float* __restrict__ w, float* __restrict__ out,
    const float* __restrict__ stIn, float* __restrict__ stOut,
    int I, int O, int P, int wio, int zsplit, float invN)
{
  __shared__ float wl[2048];
  __shared__ float bnm[256], bnr[256];
  int tid = threadIdx.x;
  int o0 = blockIdx.y*OT;
  int z  = blockIdx.z;
  int t  = (z >= zsplit) ? 1 : 0;
  int b  = t ? (z - zsplit) : z;
  const float* in = t ? in1 : in0;

  for(int idx=tid; idx<I*OT; idx+=256){
    int i = idx/OT, j = idx - i*OT;
    wl[idx] = wio ? w[(size_t)i*O + o0 + j] : w[(size_t)(o0+j)*I + i];
  }
  if(HASBN){
    for(int i=tid; i<I; i+=256){
      float s  = stIn[((size_t)t*I + i)*2];
      float s2 = stIn[((size_t)t*I + i)*2+1];
      float m  = s*invN;
      bnm[i] = m;
      bnr[i] = rsqrtf(s2*invN - m*m + EPS_BN);
    }
  }
  __syncthreads();

  int p4 = blockIdx.x*256 + tid;
  const float4* inb = (const float4*)(in + (size_t)b*I*P) + p4;
  int P4 = P >> 2;

  float acc[OT][4];
#pragma unroll
  for(int j=0;j<OT;j++){ acc[j][0]=acc[j][1]=acc[j][2]=acc[j][3]=0.f; }

  float4 vb[8];
  for(int i0=0;i0<I;i0+=8){
#pragma unroll
    for(int u=0;u<8;u++) vb[u] = inb[(size_t)(i0+u)*P4];
#pragma unroll
    for(int u=0;u<8;u++){
      float4 v = vb[u];
      if(HASBN){
        float m = bnm[i0+u], r = bnr[i0+u];
        v.x = fmaxf((v.x-m)*r, 0.f); v.y = fmaxf((v.y-m)*r, 0.f);
        v.z = fmaxf((v.z-m)*r, 0.f); v.w = fmaxf((v.w-m)*r, 0.f);
      }
      const float* wr = &wl[(i0+u)*OT];
#pragma unroll
      for(int j=0;j<OT;j++){
        float wv = wr[j];
        acc[j][0] = fmaf(wv, v.x, acc[j][0]);
        acc[j][1] = fmaf(wv, v.y, acc[j][1]);
        acc[j][2] = fmaf(wv, v.z, acc[j][2]);
        acc[j][3] = fmaf(wv, v.w, acc[j][3]);
      }
    }
  }

  float4* ob = (float4*)(out + ((size_t)z*O + o0)*P) + p4;
#pragma unroll
  for(int j=0;j<OT;j++){
    float4 vv = {acc[j][0], acc[j][1], acc[j][2], acc[j][3]};
    ob[(size_t)j*P4] = vv;
  }

  if(HASSTATS){
#pragma unroll
    for(int j=0;j<OT;j++){
      float s  = acc[j][0]+acc[j][1]+acc[j][2]+acc[j][3];
      float s2 = acc[j][0]*acc[j][0]+acc[j][1]*acc[j][1]
               + acc[j][2]*acc[j][2]+acc[j][3]*acc[j][3];
      for(int off=32; off>0; off>>=1){
        s  += __shfl_down(s,  off, 64);
        s2 += __shfl_down(s2, off, 64);
      }
      if((tid & 63)==0){
        atomicAdd(&stOut[((size_t)t*O + o0 + j)*2],   s);
        atomicAdd(&stOut[((size_t)t*O + o0 + j)*2+1], s2);
      }
    }
  }
}

// ===========================================================================
// Encoder k=2 s=2 conv (unchanged from round 5)
// ===========================================================================
__global__ __launch_bounds__(256) void conv2x2s2_bn_kernel(
    const float* __restrict__ in, const float* __restrict__ w,
    float* __restrict__ out, const float* __restrict__ stIn,
    float* __restrict__ stOut, float invN)
{
  __shared__ float wl[512];
  __shared__ float bnm[32], bnr[32];
  int tid = threadIdx.x;
  int o0 = blockIdx.x*4;
  int z  = blockIdx.y;
  int t  = (z >= 8) ? 1 : 0;

  for(int idx=tid; idx<512; idx+=256){
    int pq = idx & 3, r = idx >> 2;
    int i = r >> 2, j = r & 3;
    wl[idx] = w[(((size_t)(o0+j)*32 + i)*4) + pq];
  }
  if(tid < 32){
    float s  = stIn[((size_t)t*32 + tid)*2];
    float s2 = stIn[((size_t)t*32 + tid)*2+1];
    float m  = s*invN;
    bnm[tid] = m;
    bnr[tid] = rsqrtf(s2*invN - m*m + EPS_BN);
  }
  __syncthreads();

  int h  = tid >> 3;
  int wg = tid & 7;
  int cb = wg*8;

  float acc[4][4];
#pragma unroll
  for(int j=0;j<4;j++) for(int k=0;k<4;k++) acc[j][k]=0.f;

  float4 pre[8];
  for(int i0=0;i0<32;i0+=4){
#pragma unroll
    for(int u=0;u<4;u++){
      pre[2*u]   = *(const float4*)(in + (((size_t)z*32+i0+u)*64 + 2*h)*64 + cb);
      pre[2*u+1] = *(const float4*)(in + (((size_t)z*32+i0+u)*64 + 2*h)*64 + cb + 4);
    }
#pragma unroll
    for(int u=0;u<4;u++){
      int i = i0+u;
      const float4* r1p = (const float4*)(in + (((size_t)z*32+i)*64 + 2*h+1)*64 + cb);
      float4 a0 = pre[2*u], a1 = pre[2*u+1];
      float4 b0 = r1p[0], b1 = r1p[1];
      float m = bnm[i], r = bnr[i];
      float t0[8] = {a0.x,a0.y,a0.z,a0.w,a1.x,a1.y,a1.z,a1.w};
      float t1[8] = {b0.x,b0.y,b0.z,b0.w,b1.x,b1.y,b1.z,b1.w};
#pragma unroll
      for(int e=0;e<8;e++){
        t0[e] = fmaxf((t0[e]-m)*r, 0.f);
        t1[e] = fmaxf((t1[e]-m)*r, 0.f);
      }
#pragma unroll
      for(int j=0;j<4;j++){
        const float* wj = &wl[(i*4+j)*4];
#pragma unroll
        for(int k=0;k<4;k++){
          acc[j][k] = fmaf(wj[0], t0[2*k],   acc[j][k]);
          acc[j][k] = fmaf(wj[1], t0[2*k+1], acc[j][k]);
          acc[j][k] = fmaf(wj[2], t1[2*k],   acc[j][k]);
          acc[j][k] = fmaf(wj[3], t1[2*k+1], acc[j][k]);
        }
      }
    }
  }

#pragma unroll
  for(int j=0;j<4;j++){
    float4 vv = {acc[j][0],acc[j][1],acc[j][2],acc[j][3]};
    *(float4*)(out + ((size_t)z*32 + o0+j)*1024 + h*32 + wg*4) = vv;
  }
#pragma unroll
  for(int j=0;j<4;j++){
    float s  = acc[j][0]+acc[j][1]+acc[j][2]+acc[j][3];
    float s2 = acc[j][0]*acc[j][0]+acc[j][1]*acc[j][1]
             + acc[j][2]*acc[j][2]+acc[j][3]*acc[j][3];
    for(int off=32; off>0; off>>=1){
      s  += __shfl_down(s,  off, 64);
      s2 += __shfl_down(s2, off, 64);
    }
    if((tid & 63)==0){
      atomicAdd(&stOut[((size_t)t*32 + o0 + j)*2],   s);
      atomicAdd(&stOut[((size_t)t*32 + o0 + j)*2+1], s2);
    }
  }
}

// ===========================================================================
// ConvTranspose k=2 s=2 (unchanged from round 5)
// ===========================================================================
__global__ __launch_bounds__(256) void upsample2x2_bn_kernel(
    const float* __restrict__ in, const float* __restrict__ w,
    float* __restrict__ out, const float* __restrict__ stIn,
    float* __restrict__ stOut, float invN)
{
  __shared__ float wl[1024];
  __shared__ float bnm[128], bnr[128];
  int tid = threadIdx.x;
  int o0 = blockIdx.x*2;
  int b  = blockIdx.y;

  for(int idx=tid; idx<1024; idx+=256){
    int pq = idx & 3, r = idx >> 2;
    int i = r >> 1, j = r & 1;
    wl[idx] = w[((size_t)i*128 + o0+j)*4 + pq];
  }
  if(tid < 128){
    float s  = stIn[(size_t)tid*2];
    float s2 = stIn[(size_t)tid*2+1];
    float m  = s*invN;
    bnm[tid] = m;
    bnr[tid] = rsqrtf(s2*invN - m*m + EPS_BN);
  }
  __syncthreads();

  int h  = tid >> 3;
  int wg = tid & 7;
  int w0 = wg*4;

  float acc[2][16];
#pragma unroll
  for(int j=0;j<2;j++) for(int e=0;e<16;e++) acc[j][e]=0.f;

  float4 vb4[8];
  for(int i0=0;i0<128;i0+=8){
#pragma unroll
    for(int u=0;u<8;u++)
      vb4[u] = *(const float4*)(in + (((size_t)b*128+i0+u)*1024) + h*32 + w0);
#pragma unroll
    for(int u=0;u<8;u++){
      int i = i0+u;
      float4 v = vb4[u];
      float m = bnm[i], r = bnr[i];
      float vk[4] = {fmaxf((v.x-m)*r,0.f), fmaxf((v.y-m)*r,0.f),
                     fmaxf((v.z-m)*r,0.f), fmaxf((v.w-m)*r,0.f)};
#pragma unroll
      for(int j=0;j<2;j++){
        const float* wj = &wl[(i*2+j)*4];
#pragma unroll
        for(int pq=0;pq<4;pq++){
#pragma unroll
          for(int k=0;k<4;k++)
            acc[j][pq*4+k] = fmaf(wj[pq], vk[k], acc[j][pq*4+k]);
        }
      }
    }
  }

#pragma unroll
  for(int j=0;j<2;j++){
    float* ob = out + ((size_t)b*128 + o0+j)*4096;
#pragma unroll
    for(int p=0;p<2;p++){
      float4 A = {acc[j][(p*2+0)*4+0], acc[j][(p*2+1)*4+0],
                  acc[j][(p*2+0)*4+1], acc[j][(p*2+1)*4+1]};
      float4 B = {acc[j][(p*2+0)*4+2], acc[j][(p*2+1)*4+2],
                  acc[j][(p*2+0)*4+3], acc[j][(p*2+1)*4+3]};
      *(float4*)(ob + (2*h+p)*64 + 2*w0)     = A;
      *(float4*)(ob + (2*h+p)*64 + 2*w0 + 4) = B;
    }
  }

#pragma unroll
  for(int j=0;j<2;j++){
    float s=0.f, s2=0.f;
#pragma unroll
    for(int e=0;e<16;e++){ s += acc[j][e]; s2 += acc[j][e]*acc[j][e]; }
    for(int off=32; off>0; off>>=1){
      s  += __shfl_down(s,  off, 64);
      s2 += __shfl_down(s2, off, 64);
    }
    if((tid & 63)==0){
      atomicAdd(&stOut[((size_t)(o0+j))*2],   s);
      atomicAdd(&stOut[((size_t)(o0+j))*2+1], s2);
    }
  }
}

// ===========================================================================
__global__ __launch_bounds__(256) void bn_final_kernel(
    float* __restrict__ x, const float* __restrict__ st, float invN)
{
  int idx4 = blockIdx.x*256 + threadIdx.x;
  int c = (idx4 >> 10) & 255;
  float s  = st[(size_t)c*2];
  float s2 = st[(size_t)c*2+1];
  float m  = s*invN;
  float r  = rsqrtf(s2*invN - m*m + EPS_BN);
  float4 v = ((float4*)x)[idx4];
  v.x = fmaxf((v.x-m)*r, 0.f); v.y = fmaxf((v.y-m)*r, 0.f);
  v.z = fmaxf((v.z-m)*r, 0.f); v.w = fmaxf((v.w-m)*r, 0.f);
  ((float4*)x)[idx4] = v;
}

// ===========================================================================
__global__ __launch_bounds__(256) void dwconv3x3_kernel(
    const float* __restrict__ in, const float* __restrict__ w,
    float* __restrict__ out, int C, int H, int Wd)
{
  int idx = blockIdx.x*256 + threadIdx.x;
  int c = blockIdx.y, b = blockIdx.z;
  if(idx >= H*Wd) return;
  int h = idx / Wd, x = idx - h*Wd;
  const float* inp = in + ((size_t)b*C + c)*H*Wd;
  float acc = 0.f;
#pragma unroll
  for(int p=0;p<3;p++){
    int hh = h + p - 1;
    if((unsigned)hh >= (unsigned)H) continue;
#pragma unroll
    for(int q=0;q<3;q++){
      int wv = x + q - 1;
      if((unsigned)wv >= (unsigned)Wd) continue;
      acc += w[c*9 + p*3 + q] * inp[hh*Wd + wv];
    }
  }
  out[((size_t)b*C + c)*H*Wd + idx] = acc;
}

// ===========================================================================
__global__ __launch_bounds__(256) void conv3x3_kernel(
    const float* __restrict__ in, const float* __restrict__ w,
    float* __restrict__ out, int IC, int H, int Wd)
{
  int o = blockIdx.y, b = blockIdx.z;
  __shared__ float wl[576];
  for(int t=threadIdx.x; t<IC*9; t+=256) wl[t] = w[(size_t)o*IC*9 + t];
  __syncthreads();
  int idx = blockIdx.x*256 + threadIdx.x;
  if(idx >= H*Wd) return;
  int h = idx / Wd, x = idx - h*Wd;
  const float* inb = in + (size_t)b*IC*H*Wd;
  float acc = 0.f;
  for(int i=0;i<IC;i++){
    const float* inp = inb + (size_t)i*H*Wd;
    const float* wp  = wl + i*9;
#pragma unroll
    for(int p=0;p<3;p++){
      int hh = h + p - 1;
      if((unsigned)hh >= (unsigned)H) continue;
      const float* row = inp + hh*Wd;
#pragma unroll
      for(int q=0;q<3;q++){
        int wv = x + q - 1;
        if((unsigned)wv >= (unsigned)Wd) continue;
        acc = fmaf(wp[p*3+q], row[wv], acc);
      }
    }
  }
  out[((size_t)b*gridDim.y + o)*H*Wd + idx] = acc;
}

// ===========================================================================
__global__ __launch_bounds__(256) void l2norm_kernel(
    float* __restrict__ q, float* __restrict__ kv)
{
  int r = blockIdx.x;
  float* p;
  if(r < 512){ int b=r>>6, c=r&63; p = q + ((size_t)b*64+c)*1024; }
  else { int rr=r-512; int b=rr>>6, c=rr&63; p = kv + ((size_t)b*128+c)*1024; }
  int tid = threadIdx.x;
  float4 v = ((float4*)p)[tid];
  float s = v.x*v.x + v.y*v.y + v.z*v.z + v.w*v.w;
  __shared__ float ls[256];
  ls[tid]=s; __syncthreads();
  for(int st=128; st>0; st>>=1){ if(tid<st) ls[tid]+=ls[tid+st]; __syncthreads(); }
  float scale = 1.f / fmaxf(sqrtf(ls[0]), 1e-12f);
  v.x*=scale; v.y*=scale; v.z*=scale; v.w*=scale;
  ((float4*)p)[tid] = v;
}

// ===========================================================================
// Spatial attention pass 1: partial denominators, m split x2.
// blockIdx.x = nchunk*2 + mhalf. grid (8,8,8). kl padded stride 12 (24 KB).
// den_out must be zeroed; atomicAdd partials. q/k scores pre-scaled by th.
// ===========================================================================
__global__ __launch_bounds__(256) void attn_pass1(
    const float* __restrict__ q, const float* __restrict__ kv,
    const float* __restrict__ temp, float* __restrict__ den_out)
{
  int bx = blockIdx.x, hh = blockIdx.y, b = blockIdx.z;
  int nchunk = bx >> 1, mh = bx & 1;
  int tid = threadIdx.x;
  __shared__ __align__(16) float kl[512*12];
  const float* kb = kv + ((size_t)b*128 + hh*8)*1024 + mh*512;
  for(int t=tid;t<4096;t+=256){ int c=t>>9, m=t&511; kl[m*12+c]=kb[(size_t)c*1024+m]; }
  __syncthreads();
  int n = nchunk*256 + tid;
  const float* qp = q + ((size_t)b*64 + hh*8)*1024 + n;
  float th = temp[hh];
  float mxb = fabsf(th);
  float qr[8];
#pragma unroll
  for(int c=0;c<8;c++) qr[c]=qp[(size_t)c*1024]*th;
  const float4* kl4 = (const float4*)kl;
  float den = 0.f, den2 = 0.f;
  for(int m=0;m<512;m+=2){
    float4 a  = kl4[m*3],     a2 = kl4[m*3+1];
    float4 bt = kl4[(m+1)*3], b2 = kl4[(m+1)*3+1];
    float s0 = qr[0]*a.x+qr[1]*a.y+qr[2]*a.z+qr[3]*a.w
             + qr[4]*a2.x+qr[5]*a2.y+qr[6]*a2.z+qr[7]*a2.w;
    float s1 = qr[0]*bt.x+qr[1]*bt.y+qr[2]*bt.z+qr[3]*bt.w
             + qr[4]*b2.x+qr[5]*b2.y+qr[6]*b2.z+qr[7]*b2.w;
    den  += __expf(s0 - mxb);
    den2 += __expf(s1 - mxb);
  }
  atomicAdd(&den_out[((size_t)(b*8+hh))*1024+n], den+den2);
}

// ===========================================================================
// Spatial attention pass 2: out[c,m] += sum_n softmax[n,m]*v[c,n], n split x2.
// blockIdx.x = mchunk*2 + nhalf. grid (8,8,8). out zeroed; atomicAdd.
// ql/vl padded stride 12; 1/den staged into LDS.
// ===========================================================================
__global__ __launch_bounds__(256) void attn_pass2(
    const float* __restrict__ q, const float* __restrict__ kv,
    const float* __restrict__ temp, const float* __restrict__ den,
    float* __restrict__ out)
{
  int bx = blockIdx.x, hh = blockIdx.y, b = blockIdx.z;
  int mchunk = bx >> 1, nh = bx & 1;
  int tid = threadIdx.x;
  __shared__ __align__(16) float ql[512*12];
  __shared__ __align__(16) float vl[512*12];
  __shared__ float idl[512];
  int bh = b*8+hh;
  int n0 = nh*512;
  const float* qb = q  + ((size_t)b*64 + hh*8)*1024 + n0;
  const float* vb = kv + ((size_t)b*128 + 64 + hh*8)*1024 + n0;
  for(int t=tid;t<4096;t+=256){
    int c=t>>9, n=t&511;
    ql[n*12+c] = qb[(size_t)c*1024+n];
    vl[n*12+c] = vb[(size_t)c*1024+n];
  }
  for(int u=tid;u<512;u+=256) idl[u] = 1.f/den[(size_t)bh*1024 + n0 + u];
  __syncthreads();
  int m = mchunk*256 + tid;
  const float* kb = kv + ((size_t)b*128 + hh*8)*1024 + m;
  float th = temp[hh];
  float mxb = fabsf(th);
  float kr[8];
#pragma unroll
  for(int c=0;c<8;c++) kr[c]=kb[(size_t)c*1024]*th;
  float acc[8] = {0,0,0,0,0,0,0,0};
  const float4* ql4 = (const float4*)ql;
  const float4* vl4 = (const float4*)vl;
  for(int n=0;n<512;n+=2){
    float4 qa = ql4[n*3],     qa2 = ql4[n*3+1];
    float4 qb4= ql4[(n+1)*3], qb2 = ql4[(n+1)*3+1];
    float s0 = kr[0]*qa.x+kr[1]*qa.y+kr[2]*qa.z+kr[3]*qa.w
             + kr[4]*qa2.x+kr[5]*qa2.y+kr[6]*qa2.z+kr[7]*qa2.w;
    float s1 = kr[0]*qb4.x+kr[1]*qb4.y+kr[2]*qb4.z+kr[3]*qb4.w
             + kr[4]*qb2.x+kr[5]*qb2.y+kr[6]*qb2.z+kr[7]*qb2.w;
    float p0 = __expf(s0 - mxb) * idl[n];
    float p1 = __expf(s1 - mxb) * idl[n+1];
    float4 va = vl4[n*3],     va2 = vl4[n*3+1];
    float4 vb4f= vl4[(n+1)*3], vb2 = vl4[(n+1)*3+1];
    acc[0]+=p0*va.x + p1*vb4f.x; acc[1]+=p0*va.y + p1*vb4f.y;
    acc[2]+=p0*va.z + p1*vb4f.z; acc[3]+=p0*va.w + p1*vb4f.w;
    acc[4]+=p0*va2.x + p1*vb2.x; acc[5]+=p0*va2.y + p1*vb2.y;
    acc[6]+=p0*va2.z + p1*vb2.z; acc[7]+=p0*va2.w + p1*vb2.w;
  }
  float* ob = out + ((size_t)b*64 + hh*8)*1024 + m;
#pragma unroll
  for(int c=0;c<8;c++) atomicAdd(&ob[(size_t)c*1024], acc[c]);
}

// ===========================================================================
// Channel attention (8x8 gram per b,head), += into out. grid (8,8).
// ===========================================================================
__global__ __launch_bounds__(256) void attn_channel(
    const float* __restrict__ q, const float* __restrict__ kv,
    const float* __restrict__ temp, float* out)
{
  int hh = blockIdx.x, b = blockIdx.y;
  __shared__ float kl[8192];
  const float* qb = q  + ((size_t)b*64 + hh*8)*1024;
  const float* kb = kv + ((size_t)b*128 + hh*8)*1024;
  const float* vb = kv + ((size_t)b*128 + 64 + hh*8)*1024;
  int tid = threadIdx.x;
  for(int t=tid;t<8192;t+=256) kl[t]=kb[t];
  __syncthreads();
  __shared__ float part[256];
  __shared__ float a[64];
  {
    int pair = tid >> 2, seg = tid & 3;
    int c = pair >> 3, d = pair & 7;
    const float* qrow = qb + (size_t)c*1024 + seg*256;
    const float* krow = kl + d*1024 + seg*256;
    float s = 0.f;
#pragma unroll 4
    for(int n=0;n<256;n++) s += qrow[n]*krow[n];
    part[tid] = s;
  }
  __syncthreads();
  if(tid < 64){
    float g = part[tid*4]+part[tid*4+1]+part[tid*4+2]+part[tid*4+3];
    part[tid] = g * temp[hh];
  }
  __syncthreads();
  if(tid < 8){
    float mx = -3.4e38f;
    for(int d=0;d<8;d++) mx = fmaxf(mx, part[tid*8+d]);
    float den = 0.f;
    float e[8];
    for(int d=0;d<8;d++){ e[d] = __expf(part[tid*8+d]-mx); den+=e[d]; }
    float inv = 1.f/den;
    for(int d=0;d<8;d++) a[tid*8+d] = e[d]*inv;
  }
  __syncthreads();
  float* ob = out + ((size_t)b*64 + hh*8)*1024;
  for(int n=tid;n<1024;n+=256){
    float vv[8];
#pragma unroll
    for(int d=0;d<8;d++) vv[d] = vb[(size_t)d*1024+n];
#pragma unroll
    for(int c=0;c<8;c++){
      float s = 0.f;
#pragma unroll
      for(int d=0;d<8;d++) s += a[c*8+d]*vv[d];
      ob[(size_t)c*1024+n] += s;
    }
  }
}

// ===========================================================================
extern "C" void kernel_launch(void* const* d_in, const int* in_sizes, int n_in,
                              void* d_out, int out_size, void* d_ws, size_t ws_size,
                              hipStream_t stream)
{
  (void)in_sizes; (void)n_in; (void)out_size; (void)ws_size;
  const float* x      = (const float*)d_in[0];
  const float* y      = (const float*)d_in[1];
  const float* temp   = (const float*)d_in[2];
  const float* enc_w1 = (const float*)d_in[3];
  const float* enc_w2 = (const float*)d_in[4];
  const float* enc_w3 = (const float*)d_in[5];
  const float* kv_w   = (const float*)d_in[6];
  const float* kv_dw_w= (const float*)d_in[7];
  const float* q_w    = (const float*)d_in[8];
  const float* q_dw_w = (const float*)d_in[9];
  const float* proj_w = (const float*)d_in[10];
  const float* dec_w1 = (const float*)d_in[11];
  const float* dec_w2 = (const float*)d_in[12];
  const float* dec_w3 = (const float*)d_in[13];
  float* out = (float*)d_out;

  float* W   = (float*)d_ws;
  float* ST  = W;                    // 2048
  float* ST0 = ST;
  float* ST1 = ST + 128;
  float* ST2 = ST + 256;
  float* ST3 = ST + 512;
  float* ST4 = ST + 768;
  float* ST5 = ST + 1024;
  float* A    = W + 2048;            // 2,097,152-float region, multiply reused
  float* E1   = A;                   // enc1 out (16 z)
  float* KV1  = A;                   // after E2 (E1 dead)
  float* QPre = A + 1048576;
  float* ATTN = A;                   // after staging (KV1/QPre dead)
  float* PROJ = A + 524288;
  float* D1   = A + 1048576;
  float* E2   = W + 2099200;         //   524,288
  float* E3   = W + 2623488;         // 1,048,576
  float* KV   = W + 3672064;         // 1,048,576
  float* Q    = W + 4720640;         //   524,288
  float* DEN  = W + 5244928;         //    65,536
  float* D2   = W + 2099200;         // 4,194,304 (overlaps E2..DEN, dead then)

  const float inv32k = 1.f/32768.f, inv8k = 1.f/8192.f;

  hipMemsetAsync(ST, 0, 2048*sizeof(float), stream);
  hipMemsetAsync(DEN, 0, 65536*sizeof(float), stream);

  // ---- encoder ----
  conv1x1_enc1_kernel<<<dim3(32,16),256,0,stream>>>(x, y, enc_w1, E1, ST0);
  conv2x2s2_bn_kernel<<<dim3(8,16),256,0,stream>>>(E1, enc_w2, E2, ST0, ST1, inv32k);
  conv1x1_kernel<2,true,true><<<dim3(1,32,16),256,0,stream>>>(
      E2, E2 + (size_t)8*32*1024, enc_w3, E3, ST1, ST2, 32, 64, 1024, 0, 8, inv8k);

  // ---- kv = dw3x3(1x1(x_enc)); q = conv3x3(1x1(y_enc)) ----
  conv1x1_kernel<2,true,false><<<dim3(1,64,8),256,0,stream>>>(
      E3, E3, kv_w, KV1, ST2, nullptr, 64, 128, 1024, 0, 999, inv8k);
  dwconv3x3_kernel<<<dim3(4,128,8),256,0,stream>>>(KV1, kv_dw_w, KV, 128, 32, 32);
  conv1x1_kernel<2,true,false><<<dim3(1,32,8),256,0,stream>>>(
      E3 + (size_t)8*64*1024, E3, q_w, QPre, ST2 + 128, nullptr, 64, 64, 1024, 0, 999, inv8k);
  conv3x3_kernel<<<dim3(4,64,8),256,0,stream>>>(QPre, q_dw_w, Q, 64, 32, 32);

  // ATTN region (overlapping KV1) is dead now — zero it for atomic accumulation
  hipMemsetAsync(ATTN, 0, 524288*sizeof(float), stream);

  // ---- l2 normalize q and k ----
  l2norm_kernel<<<1024,256,0,stream>>>(Q, KV);

  // ---- attention ----
  attn_pass1<<<dim3(8,8,8),256,0,stream>>>(Q, KV, temp, DEN);
  attn_pass2<<<dim3(8,8,8),256,0,stream>>>(Q, KV, temp, DEN, ATTN);
  attn_channel<<<dim3(8,8),256,0,stream>>>(Q, KV, temp, ATTN);

  // ---- proj ----
  conv1x1_kernel<2,false,false><<<dim3(1,32,8),256,0,stream>>>(
      ATTN, ATTN, proj_w, PROJ, nullptr, nullptr, 64, 64, 1024, 0, 999, 0.f);

  // ---- decoder ----
  conv1x1_kernel<2,false,true><<<dim3(1,64,8),256,0,stream>>>(
      PROJ, PROJ, dec_w1, D1, nullptr, ST3, 64, 128, 1024, 1, 999, 0.f);
  upsample2x2_bn_kernel<<<dim3(64,8),256,0,stream>>>(D1, dec_w2, D2, ST3, ST4, inv8k);
  conv1x1_kernel<8,true,true><<<dim3(4,32,8),256,0,stream>>>(
      D2, D2, dec_w3, out, ST4, ST5, 128, 256, 4096, 1, 999, inv32k);
  bn_final_kernel<<<8192,256,0,stream>>>(out, ST5, inv32k);
}

// Round 7
// 620.803 us; speedup vs baseline: 2.3228x; 1.0269x over previous
//
#include <hip/hip_runtime.h>
#include <hip/hip_bf16.h>

#define EPS_BN 1e-5f

// ===========================================================================
// enc1: double-buffered LDS-tiled GEMM. out[z,o,p] = sum_i w[o,i]*in[z,i,p]
// I=256, O=32, P=4096. Tile: 64 cols x 32 outs. K chunks of 32 ch.
// grid (64 tiles, 16 z) = 1024 blocks. LDS 25 KB (2 bufs). One barrier/chunk;
// next chunk's global loads issued before compute (latency overlapped).
// Thread: cg=tid&15 (f4 col), og=tid>>4 (2 outs). wt padded stride 34
// (write banks (2ch+o)%32 -> 2-way, free; f2 read stays 8B-aligned).
// ===========================================================================
__global__ __launch_bounds__(256) void conv1x1_enc1_kernel(
    const float* __restrict__ in0, const float* __restrict__ in1,
    const float* __restrict__ w, float* __restrict__ out,
    float* __restrict__ stOut)
{
  __shared__ float il[2][32*64];     // [buf][ch][16 f4] 8 KB each
  __shared__ float wt[2][32*34];     // [buf][ch*34+o]   4.25 KB each
  int tid  = threadIdx.x;
  int tile = blockIdx.x;
  int z    = blockIdx.y;
  int t    = z >> 3;
  const float* in  = t ? in1 : in0;
  const float* inb = in + ((size_t)(z&7))*256*4096 + tile*64;
  int cg = tid & 15;
  int og = tid >> 4;

  float4 vr[2]; float wr[4];
  int chA = tid >> 4;          // il stage u=0: ch, c4 = cg
  int chB = 16 + chA;          // u=1
  int wo  = tid >> 5;          // wt stage: o base (u adds 8), ch = tid&31
  int wch = tid & 31;

  // prologue: stage chunk 0
  vr[0] = *(const float4*)(inb + (size_t)chA*4096 + cg*4);
  vr[1] = *(const float4*)(inb + (size_t)chB*4096 + cg*4);
#pragma unroll
  for(int u=0;u<4;u++) wr[u] = w[(size_t)(wo+u*8)*256 + wch];
  ((float4*)il[0])[tid]     = vr[0];
  ((float4*)il[0])[tid+256] = vr[1];
#pragma unroll
  for(int u=0;u<4;u++) wt[0][wch*34 + wo + u*8] = wr[u];
  __syncthreads();

  float acc[2][4];
#pragma unroll
  for(int j=0;j<2;j++){ acc[j][0]=acc[j][1]=acc[j][2]=acc[j][3]=0.f; }

  for(int c=0;c<8;c++){
    int cur = c & 1;
    if(c < 7){
      int k0 = (c+1)*32;
      vr[0] = *(const float4*)(inb + (size_t)(k0+chA)*4096 + cg*4);
      vr[1] = *(const float4*)(inb + (size_t)(k0+chB)*4096 + cg*4);
#pragma unroll
      for(int u=0;u<4;u++) wr[u] = w[(size_t)(wo+u*8)*256 + k0 + wch];
    }
    const float4* ilc = (const float4*)il[cur];
    const float*  wtc = wt[cur];
#pragma unroll 8
    for(int ch=0; ch<32; ch++){
      float4 v  = ilc[ch*16 + cg];
      float2 wv = *(const float2*)&wtc[ch*34 + og*2];
      acc[0][0]=fmaf(wv.x,v.x,acc[0][0]); acc[0][1]=fmaf(wv.x,v.y,acc[0][1]);
      acc[0][2]=fmaf(wv.x,v.z,acc[0][2]); acc[0][3]=fmaf(wv.x,v.w,acc[0][3]);
      acc[1][0]=fmaf(wv.y,v.x,acc[1][0]); acc[1][1]=fmaf(wv.y,v.y,acc[1][1]);
      acc[1][2]=fmaf(wv.y,v.z,acc[1][2]); acc[1][3]=fmaf(wv.y,v.w,acc[1][3]);
    }
    if(c < 7){
      int nxt = 1 - cur;
      ((float4*)il[nxt])[tid]     = vr[0];
      ((float4*)il[nxt])[tid+256] = vr[1];
#pragma unroll
      for(int u=0;u<4;u++) wt[nxt][wch*34 + wo + u*8] = wr[u];
      __syncthreads();
    }
  }

  float* ob = out + ((size_t)z*32 + og*2)*4096 + tile*64 + cg*4;
#pragma unroll
  for(int j=0;j<2;j++){
    float4 vv = {acc[j][0],acc[j][1],acc[j][2],acc[j][3]};
    *(float4*)(ob + (size_t)j*4096) = vv;
  }
#pragma unroll
  for(int j=0;j<2;j++){
    float s  = acc[j][0]+acc[j][1]+acc[j][2]+acc[j][3];
    float s2 = acc[j][0]*acc[j][0]+acc[j][1]*acc[j][1]
             + acc[j][2]*acc[j][2]+acc[j][3]*acc[j][3];
    for(int off=8; off>0; off>>=1){
      s  += __shfl_down(s,  off, 16);
      s2 += __shfl_down(s2, off, 16);
    }
    if(cg==0){
      atomicAdd(&stOut[((size_t)t*32 + og*2 + j)*2],   s);
      atomicAdd(&stOut[((size_t)t*32 + og*2 + j)*2+1], s2);
    }
  }
}

// ===========================================================================
// Generic big-P 1x1 conv (used for dec3, P=4096), 8-deep pipelined loads.
// ===========================================================================
template<int OT, bool HASBN, bool HASSTATS>
__global__ __launch_bounds__(256) void conv1x1_kernel(
    const float* __restrict__ in0, const float* __restrict__ in1,
    const float* __restrict__ w, float* __restrict__ out,
    const float* __restrict__ stIn, float* __restrict__ stOut,
    int I, int O, int P, int wio, int zsplit, float invN)
{
  __shared__ float wl[2048];
  __shared__ float bnm[256], bnr[256];
  int tid = threadIdx.x;
  int o0 = blockIdx.y*OT;
  int z  = blockIdx.z;
  int t  = (z >= zsplit) ? 1 : 0;
  int b  = t ? (z - zsplit) : z;
  const float* in = t ? in1 : in0;

  for(int idx=tid; idx<I*OT; idx+=256){
    int i = idx/OT, j = idx - i*OT;
    wl[idx] = wio ? w[(size_t)i*O + o0 + j] : w[(size_t)(o0+j)*I + i];
  }
  if(HASBN){
    for(int i=tid; i<I; i+=256){
      float s  = stIn[((size_t)t*I + i)*2];
      float s2 = stIn[((size_t)t*I + i)*2+1];
      float m  = s*invN;
      bnm[i] = m;
      bnr[i] = rsqrtf(s2*invN - m*m + EPS_BN);
    }
  }
  __syncthreads();

  int p4 = blockIdx.x*256 + tid;
  const float4* inb = (const float4*)(in + (size_t)b*I*P) + p4;
  int P4 = P >> 2;

  float acc[OT][4];
#pragma unroll
  for(int j=0;j<OT;j++){ acc[j][0]=acc[j][1]=acc[j][2]=acc[j][3]=0.f; }

  float4 vb[8];
  for(int i0=0;i0<I;i0+=8){
#pragma unroll
    for(int u=0;u<8;u++) vb[u] = inb[(size_t)(i0+u)*P4];
#pragma unroll
    for(int u=0;u<8;u++){
      float4 v = vb[u];
      if(HASBN){
        float m = bnm[i0+u], r = bnr[i0+u];
        v.x = fmaxf((v.x-m)*r, 0.f); v.y = fmaxf((v.y-m)*r, 0.f);
        v.z = fmaxf((v.z-m)*r, 0.f); v.w = fmaxf((v.w-m)*r, 0.f);
      }
      const float* wr = &wl[(i0+u)*OT];
#pragma unroll
      for(int j=0;j<OT;j++){
        float wv = wr[j];
        acc[j][0] = fmaf(wv, v.x, acc[j][0]);
        acc[j][1] = fmaf(wv, v.y, acc[j][1]);
        acc[j][2] = fmaf(wv, v.z, acc[j][2]);
        acc[j][3] = fmaf(wv, v.w, acc[j][3]);
      }
    }
  }

  float4* ob = (float4*)(out + ((size_t)z*O + o0)*P) + p4;
#pragma unroll
  for(int j=0;j<OT;j++){
    float4 vv = {acc[j][0], acc[j][1], acc[j][2], acc[j][3]};
    ob[(size_t)j*P4] = vv;
  }

  if(HASSTATS){
#pragma unroll
    for(int j=0;j<OT;j++){
      float s  = acc[j][0]+acc[j][1]+acc[j][2]+acc[j][3];
      float s2 = acc[j][0]*acc[j][0]+acc[j][1]*acc[j][1]
               + acc[j][2]*acc[j][2]+acc[j][3]*acc[j][3];
      for(int off=32; off>0; off>>=1){
        s  += __shfl_down(s,  off, 64);
        s2 += __shfl_down(s2, off, 64);
      }
      if((tid & 63)==0){
        atomicAdd(&stOut[((size_t)t*O + o0 + j)*2],   s);
        atomicAdd(&stOut[((size_t)t*O + o0 + j)*2+1], s2);
      }
    }
  }
}

// ===========================================================================
// Small-P (P=1024) 1x1 conv: block = 128 f4-cols x 2 o-slices (os=tid>>7).
// grid (2, O/(2*OT), Z). 8-deep pipelined loads. Waves are os-uniform so
// stats use a full wave-reduce.
// ===========================================================================
template<int OT, bool HASBN, bool HASSTATS>
__global__ __launch_bounds__(256) void conv1x1_small(
    const float* __restrict__ in0, const float* __restrict__ in1,
    const float* __restrict__ w, float* __restrict__ out,
    const float* __restrict__ stIn, float* __restrict__ stOut,
    int I, int O, int wio, int zsplit, float invN)
{
  __shared__ float wl[512];
  __shared__ float bnm[128], bnr[128];
  int tid = threadIdx.x;
  int z  = blockIdx.z;
  int t  = (z >= zsplit) ? 1 : 0;
  int b  = t ? (z - zsplit) : z;
  const float* in = t ? in1 : in0;
  int W2 = 2*OT;

  for(int idx=tid; idx<I*W2; idx+=256){
    int i = idx/W2, slot = idx - i*W2;
    int oabs = blockIdx.y*W2 + slot;
    wl[idx] = wio ? w[(size_t)i*O + oabs] : w[(size_t)oabs*I + i];
  }
  if(HASBN){
    for(int i=tid; i<I; i+=256){
      float s  = stIn[((size_t)t*I + i)*2];
      float s2 = stIn[((size_t)t*I + i)*2+1];
      float m  = s*invN;
      bnm[i] = m;
      bnr[i] = rsqrtf(s2*invN - m*m + EPS_BN);
    }
  }
  __syncthreads();

  int p4 = blockIdx.x*128 + (tid & 127);
  int os = tid >> 7;
  const float4* inb = (const float4*)(in + (size_t)b*I*1024) + p4;

  float acc[OT][4];
#pragma unroll
  for(int j=0;j<OT;j++){ acc[j][0]=acc[j][1]=acc[j][2]=acc[j][3]=0.f; }

  float4 vb[8];
  for(int i0=0;i0<I;i0+=8){
#pragma unroll
    for(int u=0;u<8;u++) vb[u] = inb[(size_t)(i0+u)*256];
#pragma unroll
    for(int u=0;u<8;u++){
      float4 v = vb[u];
      if(HASBN){
        float m = bnm[i0+u], r = bnr[i0+u];
        v.x = fmaxf((v.x-m)*r, 0.f); v.y = fmaxf((v.y-m)*r, 0.f);
        v.z = fmaxf((v.z-m)*r, 0.f); v.w = fmaxf((v.w-m)*r, 0.f);
      }
      const float* wr = &wl[(i0+u)*W2 + os*OT];
#pragma unroll
      for(int j=0;j<OT;j++){
        float wv = wr[j];
        acc[j][0] = fmaf(wv, v.x, acc[j][0]);
        acc[j][1] = fmaf(wv, v.y, acc[j][1]);
        acc[j][2] = fmaf(wv, v.z, acc[j][2]);
        acc[j][3] = fmaf(wv, v.w, acc[j][3]);
      }
    }
  }

  int obase = blockIdx.y*W2 + os*OT;
  float4* ob = (float4*)(out + ((size_t)z*O + obase)*1024) + p4;
#pragma unroll
  for(int j=0;j<OT;j++){
    float4 vv = {acc[j][0], acc[j][1], acc[j][2], acc[j][3]};
    ob[(size_t)j*256] = vv;
  }

  if(HASSTATS){
#pragma unroll
    for(int j=0;j<OT;j++){
      float s  = acc[j][0]+acc[j][1]+acc[j][2]+acc[j][3];
      float s2 = acc[j][0]*acc[j][0]+acc[j][1]*acc[j][1]
               + acc[j][2]*acc[j][2]+acc[j][3]*acc[j][3];
      for(int off=32; off>0; off>>=1){
        s  += __shfl_down(s,  off, 64);
        s2 += __shfl_down(s2, off, 64);
      }
      if((tid & 63)==0){
        atomicAdd(&stOut[((size_t)t*O + obase + j)*2],   s);
        atomicAdd(&stOut[((size_t)t*O + obase + j)*2+1], s2);
      }
    }
  }
}

// ===========================================================================
// Encoder k=2 s=2 conv, 32->32, 64x64 -> 32x32. grid (8 o-grp, 4 row-qtr, 16 z)
// wave = o_sub (one out channel per wave); thread = 1 output f4.
// ===========================================================================
__global__ __launch_bounds__(256) void conv2x2s2_bn_kernel(
    const float* __restrict__ in, const float* __restrict__ w,
    float* __restrict__ out, const float* __restrict__ stIn,
    float* __restrict__ stOut, float invN)
{
  __shared__ float wl[512];          // [o_sub][ch][pq]
  __shared__ float bnm[32], bnr[32];
  int tid = threadIdx.x;
  int o0 = blockIdx.x*4;
  int rq = blockIdx.y;
  int z  = blockIdx.z;
  int t  = z >> 3;

  for(int idx=tid; idx<512; idx+=256){
    int osub = idx>>7, ch=(idx>>2)&31, pq=idx&3;
    wl[idx] = w[(((size_t)(o0+osub)*32 + ch)*4) + pq];
  }
  if(tid < 32){
    float s  = stIn[((size_t)t*32 + tid)*2];
    float s2 = stIn[((size_t)t*32 + tid)*2+1];
    float m  = s*invN;
    bnm[tid] = m;
    bnr[tid] = rsqrtf(s2*invN - m*m + EPS_BN);
  }
  __syncthreads();

  int os   = tid >> 6;               // wave id = o_sub
  int slot = tid & 63;
  int h    = rq*8 + (slot>>3);
  int wg   = slot & 7;
  int cb   = wg*8;
  const float* wbase = &wl[os*128];
  const float* inz = in + (size_t)z*32*4096;

  float acc[4] = {0,0,0,0};
  float4 c0,c1,c2,c3, n0_,n1_,n2_,n3_;
  c0 = *(const float4*)(inz + (size_t)0*4096 + (2*h)*64 + cb);
  c1 = *(const float4*)(inz + (size_t)0*4096 + (2*h)*64 + cb + 4);
  c2 = *(const float4*)(inz + (size_t)0*4096 + (2*h+1)*64 + cb);
  c3 = *(const float4*)(inz + (size_t)0*4096 + (2*h+1)*64 + cb + 4);
  for(int ch=0; ch<32; ch++){
    if(ch < 31){
      n0_ = *(const float4*)(inz + (size_t)(ch+1)*4096 + (2*h)*64 + cb);
      n1_ = *(const float4*)(inz + (size_t)(ch+1)*4096 + (2*h)*64 + cb + 4);
      n2_ = *(const float4*)(inz + (size_t)(ch+1)*4096 + (2*h+1)*64 + cb);
      n3_ = *(const float4*)(inz + (size_t)(ch+1)*4096 + (2*h+1)*64 + cb + 4);
    }
    float m = bnm[ch], r = bnr[ch];
    float t0[8] = {c0.x,c0.y,c0.z,c0.w,c1.x,c1.y,c1.z,c1.w};
    float t1[8] = {c2.x,c2.y,c2.z,c2.w,c3.x,c3.y,c3.z,c3.w};
#pragma unroll
    for(int e=0;e<8;e++){
      t0[e] = fmaxf((t0[e]-m)*r, 0.f);
      t1[e] = fmaxf((t1[e]-m)*r, 0.f);
    }
    const float* wp = wbase + ch*4;
#pragma unroll
    for(int k=0;k<4;k++){
      acc[k] = fmaf(wp[0], t0[2*k],   acc[k]);
      acc[k] = fmaf(wp[1], t0[2*k+1], acc[k]);
      acc[k] = fmaf(wp[2], t1[2*k],   acc[k]);
      acc[k] = fmaf(wp[3], t1[2*k+1], acc[k]);
    }
    c0=n0_; c1=n1_; c2=n2_; c3=n3_;
  }

  float4 vv = {acc[0],acc[1],acc[2],acc[3]};
  *(float4*)(out + ((size_t)z*32 + o0+os)*1024 + h*32 + wg*4) = vv;

  float s  = acc[0]+acc[1]+acc[2]+acc[3];
  float s2 = acc[0]*acc[0]+acc[1]*acc[1]+acc[2]*acc[2]+acc[3]*acc[3];
  for(int off=32; off>0; off>>=1){
    s  += __shfl_down(s,  off, 64);
    s2 += __shfl_down(s2, off, 64);
  }
  if((tid & 63)==0){
    atomicAdd(&stOut[((size_t)t*32 + o0 + os)*2],   s);
    atomicAdd(&stOut[((size_t)t*32 + o0 + os)*2+1], s2);
  }
}

// ===========================================================================
// ConvTranspose k=2 s=2 (unchanged)
// ===========================================================================
__global__ __launch_bounds__(256) void upsample2x2_bn_kernel(
    const float* __restrict__ in, const float* __restrict__ w,
    float* __restrict__ out, const float* __restrict__ stIn,
    float* __restrict__ stOut, float invN)
{
  __shared__ float wl[1024];
  __shared__ float bnm[128], bnr[128];
  int tid = threadIdx.x;
  int o0 = blockIdx.x*2;
  int b  = blockIdx.y;

  for(int idx=tid; idx<1024; idx+=256){
    int pq = idx & 3, r = idx >> 2;
    int i = r >> 1, j = r & 1;
    wl[idx] = w[((size_t)i*128 + o0+j)*4 + pq];
  }
  if(tid < 128){
    float s  = stIn[(size_t)tid*2];
    float s2 = stIn[(size_t)tid*2+1];
    float m  = s*invN;
    bnm[tid] = m;
    bnr[tid] = rsqrtf(s2*invN - m*m + EPS_BN);
  }
  __syncthreads();

  int h  = tid >> 3;
  int wg = tid & 7;
  int w0 = wg*4;

  float acc[2][16];
#pragma unroll
  for(int j=0;j<2;j++) for(int e=0;e<16;e++) acc[j][e]=0.f;

  float4 vb4[8];
  for(int i0=0;i0<128;i0+=8){
#pragma unroll
    for(int u=0;u<8;u++)
      vb4[u] = *(const float4*)(in + (((size_t)b*128+i0+u)*1024) + h*32 + w0);
#pragma unroll
    for(int u=0;u<8;u++){
      int i = i0+u;
      float4 v = vb4[u];
      float m = bnm[i], r = bnr[i];
      float vk[4] = {fmaxf((v.x-m)*r,0.f), fmaxf((v.y-m)*r,0.f),
                     fmaxf((v.z-m)*r,0.f), fmaxf((v.w-m)*r,0.f)};
#pragma unroll
      for(int j=0;j<2;j++){
        const float* wj = &wl[(i*2+j)*4];
#pragma unroll
        for(int pq=0;pq<4;pq++){
#pragma unroll
          for(int k=0;k<4;k++)
            acc[j][pq*4+k] = fmaf(wj[pq], vk[k], acc[j][pq*4+k]);
        }
      }
    }
  }

#pragma unroll
  for(int j=0;j<2;j++){
    float* ob = out + ((size_t)b*128 + o0+j)*4096;
#pragma unroll
    for(int p=0;p<2;p++){
      float4 A = {acc[j][(p*2+0)*4+0], acc[j][(p*2+1)*4+0],
                  acc[j][(p*2+0)*4+1], acc[j][(p*2+1)*4+1]};
      float4 B = {acc[j][(p*2+0)*4+2], acc[j][(p*2+1)*4+2],
                  acc[j][(p*2+0)*4+3], acc[j][(p*2+1)*4+3]};
      *(float4*)(ob + (2*h+p)*64 + 2*w0)     = A;
      *(float4*)(ob + (2*h+p)*64 + 2*w0 + 4) = B;
    }
  }

#pragma unroll
  for(int j=0;j<2;j++){
    float s=0.f, s2=0.f;
#pragma unroll
    for(int e=0;e<16;e++){ s += acc[j][e]; s2 += acc[j][e]*acc[j][e]; }
    for(int off=32; off>0; off>>=1){
      s  += __shfl_down(s,  off, 64);
      s2 += __shfl_down(s2, off, 64);
    }
    if((tid & 63)==0){
      atomicAdd(&stOut[((size_t)(o0+j))*2],   s);
      atomicAdd(&stOut[((size_t)(o0+j))*2+1], s2);
    }
  }
}

// ===========================================================================
__global__ __launch_bounds__(256) void bn_final_kernel(
    float* __restrict__ x, const float* __restrict__ st, float invN)
{
  int idx4 = blockIdx.x*256 + threadIdx.x;
  int c = (idx4 >> 10) & 255;
  float s  = st[(size_t)c*2];
  float s2 = st[(size_t)c*2+1];
  float m  = s*invN;
  float r  = rsqrtf(s2*invN - m*m + EPS_BN);
  float4 v = ((float4*)x)[idx4];
  v.x = fmaxf((v.x-m)*r, 0.f); v.y = fmaxf((v.y-m)*r, 0.f);
  v.z = fmaxf((v.z-m)*r, 0.f); v.w = fmaxf((v.w-m)*r, 0.f);
  ((float4*)x)[idx4] = v;
}

// ===========================================================================
__global__ __launch_bounds__(256) void dwconv3x3_kernel(
    const float* __restrict__ in, const float* __restrict__ w,
    float* __restrict__ out, int C, int H, int Wd)
{
  int idx = blockIdx.x*256 + threadIdx.x;
  int c = blockIdx.y, b = blockIdx.z;
  if(idx >= H*Wd) return;
  int h = idx / Wd, x = idx - h*Wd;
  const float* inp = in + ((size_t)b*C + c)*H*Wd;
  float acc = 0.f;
#pragma unroll
  for(int p=0;p<3;p++){
    int hh = h + p - 1;
    if((unsigned)hh >= (unsigned)H) continue;
#pragma unroll
    for(int q=0;q<3;q++){
      int wv = x + q - 1;
      if((unsigned)wv >= (unsigned)Wd) continue;
      acc += w[c*9 + p*3 + q] * inp[hh*Wd + wv];
    }
  }
  out[((size_t)b*C + c)*H*Wd + idx] = acc;
}

// ===========================================================================
__global__ __launch_bounds__(256) void conv3x3_kernel(
    const float* __restrict__ in, const float* __restrict__ w,
    float* __restrict__ out, int IC, int H, int Wd)
{
  int o = blockIdx.y, b = blockIdx.z;
  __shared__ float wl[576];
  for(int t=threadIdx.x; t<IC*9; t+=256) wl[t] = w[(size_t)o*IC*9 + t];
  __syncthreads();
  int idx = blockIdx.x*256 + threadIdx.x;
  if(idx >= H*Wd) return;
  int h = idx / Wd, x = idx - h*Wd;
  const float* inb = in + (size_t)b*IC*H*Wd;
  float acc = 0.f;
  for(int i=0;i<IC;i++){
    const float* inp = inb + (size_t)i*H*Wd;
    const float* wp  = wl + i*9;
#pragma unroll
    for(int p=0;p<3;p++){
      int hh = h + p - 1;
      if((unsigned)hh >= (unsigned)H) continue;
      const float* row = inp + hh*Wd;
#pragma unroll
      for(int q=0;q<3;q++){
        int wv = x + q - 1;
        if((unsigned)wv >= (unsigned)Wd) continue;
        acc = fmaf(wp[p*3+q], row[wv], acc);
      }
    }
  }
  out[((size_t)b*gridDim.y + o)*H*Wd + idx] = acc;
}

// ===========================================================================
__global__ __launch_bounds__(256) void l2norm_kernel(
    float* __restrict__ q, float* __restrict__ kv)
{
  int r = blockIdx.x;
  float* p;
  if(r < 512){ int b=r>>6, c=r&63; p = q + ((size_t)b*64+c)*1024; }
  else { int rr=r-512; int b=rr>>6, c=rr&63; p = kv + ((size_t)b*128+c)*1024; }
  int tid = threadIdx.x;
  float4 v = ((float4*)p)[tid];
  float s = v.x*v.x + v.y*v.y + v.z*v.z + v.w*v.w;
  __shared__ float ls[256];
  ls[tid]=s; __syncthreads();
  for(int st=128; st>0; st>>=1){ if(tid<st) ls[tid]+=ls[tid+st]; __syncthreads(); }
  float scale = 1.f / fmaxf(sqrtf(ls[0]), 1e-12f);
  v.x*=scale; v.y*=scale; v.z*=scale; v.w*=scale;
  ((float4*)p)[tid] = v;
}

// ===========================================================================
// Spatial attention pass 1: partial denominators. m split x4, n chunks x4.
// blockIdx.x = nchunk*4 + mq. grid (16,8,8)=1024. kl[256][12] = 12 KB.
// ===========================================================================
__global__ __launch_bounds__(256) void attn_pass1(
    const float* __restrict__ q, const float* __restrict__ kv,
    const float* __restrict__ temp, float* __restrict__ den_out)
{
  int bx = blockIdx.x, hh = blockIdx.y, b = blockIdx.z;
  int nchunk = bx >> 2, mq = bx & 3;
  int tid = threadIdx.x;
  __shared__ __align__(16) float kl[256*12];
  const float* kb = kv + ((size_t)b*128 + hh*8)*1024 + mq*256;
  for(int t=tid;t<2048;t+=256){ int c=t>>8, m=t&255; kl[m*12+c]=kb[(size_t)c*1024+m]; }
  __syncthreads();
  int n = nchunk*256 + tid;
  const float* qp = q + ((size_t)b*64 + hh*8)*1024 + n;
  float th = temp[hh];
  float mxb = fabsf(th);
  float qr[8];
#pragma unroll
  for(int c=0;c<8;c++) qr[c]=qp[(size_t)c*1024]*th;
  const float4* kl4 = (const float4*)kl;
  float den = 0.f, den2 = 0.f;
  for(int m=0;m<256;m+=2){
    float4 a  = kl4[m*3],     a2 = kl4[m*3+1];
    float4 bt = kl4[(m+1)*3], b2 = kl4[(m+1)*3+1];
    float s0 = qr[0]*a.x+qr[1]*a.y+qr[2]*a.z+qr[3]*a.w
             + qr[4]*a2.x+qr[5]*a2.y+qr[6]*a2.z+qr[7]*a2.w;
    float s1 = qr[0]*bt.x+qr[1]*bt.y+qr[2]*bt.z+qr[3]*bt.w
             + qr[4]*b2.x+qr[5]*b2.y+qr[6]*b2.z+qr[7]*b2.w;
    den  += __expf(s0 - mxb);
    den2 += __expf(s1 - mxb);
  }
  atomicAdd(&den_out[((size_t)(b*8+hh))*1024+n], den+den2);
}

// ===========================================================================
// Spatial attention pass 2: n split x4, m chunks x4. grid (16,8,8)=1024.
// LDS 25 KB. out zeroed beforehand; atomicAdd partials.
// ===========================================================================
__global__ __launch_bounds__(256) void attn_pass2(
    const float* __restrict__ q, const float* __restrict__ kv,
    const float* __restrict__ temp, const float* __restrict__ den,
    float* __restrict__ out)
{
  int bx = blockIdx.x, hh = blockIdx.y, b = blockIdx.z;
  int mchunk = bx >> 2, nq = bx & 3;
  int tid = threadIdx.x;
  __shared__ __align__(16) float ql[256*12];
  __shared__ __align__(16) float vl[256*12];
  __shared__ float idl[256];
  int bh = b*8+hh;
  int n0 = nq*256;
  const float* qb = q  + ((size_t)b*64 + hh*8)*1024 + n0;
  const float* vb = kv + ((size_t)b*128 + 64 + hh*8)*1024 + n0;
  for(int t=tid;t<2048;t+=256){
    int c=t>>8, n=t&255;
    ql[n*12+c] = qb[(size_t)c*1024+n];
    vl[n*12+c] = vb[(size_t)c*1024+n];
  }
  idl[tid] = 1.f/den[(size_t)bh*1024 + n0 + tid];
  __syncthreads();
  int m = mchunk*256 + tid;
  const float* kb = kv + ((size_t)b*128 + hh*8)*1024 + m;
  float th = temp[hh];
  float mxb = fabsf(th);
  float kr[8];
#pragma unroll
  for(int c=0;c<8;c++) kr[c]=kb[(size_t)c*1024]*th;
  float acc[8] = {0,0,0,0,0,0,0,0};
  const float4* ql4 = (const float4*)ql;
  const float4* vl4 = (const float4*)vl;
  for(int n=0;n<256;n+=2){
    float4 qa = ql4[n*3],     qa2 = ql4[n*3+1];
    float4 qc = ql4[(n+1)*3], qc2 = ql4[(n+1)*3+1];
    float s0 = kr[0]*qa.x+kr[1]*qa.y+kr[2]*qa.z+kr[3]*qa.w
             + kr[4]*qa2.x+kr[5]*qa2.y+kr[6]*qa2.z+kr[7]*qa2.w;
    float s1 = kr[0]*qc.x+kr[1]*qc.y+kr[2]*qc.z+kr[3]*qc.w
             + kr[4]*qc2.x+kr[5]*qc2.y+kr[6]*qc2.z+kr[7]*qc2.w;
    float p0 = __expf(s0 - mxb) * idl[n];
    float p1 = __expf(s1 - mxb) * idl[n+1];
    float4 va = vl4[n*3],     va2 = vl4[n*3+1];
    float4 vc = vl4[(n+1)*3], vc2 = vl4[(n+1)*3+1];
    acc[0]+=p0*va.x + p1*vc.x; acc[1]+=p0*va.y + p1*vc.y;
    acc[2]+=p0*va.z + p1*vc.z; acc[3]+=p0*va.w + p1*vc.w;
    acc[4]+=p0*va2.x + p1*vc2.x; acc[5]+=p0*va2.y + p1*vc2.y;
    acc[6]+=p0*va2.z + p1*vc2.z; acc[7]+=p0*va2.w + p1*vc2.w;
  }
  float* ob = out + ((size_t)b*64 + hh*8)*1024 + m;
#pragma unroll
  for(int c=0;c<8;c++) atomicAdd(&ob[(size_t)c*1024], acc[c]);
}

// ===========================================================================
// Channel attention (8x8 gram per b,head), += into out. grid (8,8).
// ===========================================================================
__global__ __launch_bounds__(256) void attn_channel(
    const float* __restrict__ q, const float* __restrict__ kv,
    const float* __restrict__ temp, float* out)
{
  int hh = blockIdx.x, b = blockIdx.y;
  __shared__ float kl[8192];
  const float* qb = q  + ((size_t)b*64 + hh*8)*1024;
  const float* kb = kv + ((size_t)b*128 + hh*8)*1024;
  const float* vb = kv + ((size_t)b*128 + 64 + hh*8)*1024;
  int tid = threadIdx.x;
  for(int t=tid;t<8192;t+=256) kl[t]=kb[t];
  __syncthreads();
  __shared__ float part[256];
  __shared__ float a[64];
  {
    int pair = tid >> 2, seg = tid & 3;
    int c = pair >> 3, d = pair & 7;
    const float* qrow = qb + (size_t)c*1024 + seg*256;
    const float* krow = kl + d*1024 + seg*256;
    float s = 0.f;
#pragma unroll 4
    for(int n=0;n<256;n++) s += qrow[n]*krow[n];
    part[tid] = s;
  }
  __syncthreads();
  if(tid < 64){
    float g = part[tid*4]+part[tid*4+1]+part[tid*4+2]+part[tid*4+3];
    part[tid] = g * temp[hh];
  }
  __syncthreads();
  if(tid < 8){
    float mx = -3.4e38f;
    for(int d=0;d<8;d++) mx = fmaxf(mx, part[tid*8+d]);
    float den = 0.f;
    float e[8];
    for(int d=0;d<8;d++){ e[d] = __expf(part[tid*8+d]-mx); den+=e[d]; }
    float inv = 1.f/den;
    for(int d=0;d<8;d++) a[tid*8+d] = e[d]*inv;
  }
  __syncthreads();
  float* ob = out + ((size_t)b*64 + hh*8)*1024;
  for(int n=tid;n<1024;n+=256){
    float vv[8];
#pragma unroll
    for(int d=0;d<8;d++) vv[d] = vb[(size_t)d*1024+n];
#pragma unroll
    for(int c=0;c<8;c++){
      float s = 0.f;
#pragma unroll
      for(int d=0;d<8;d++) s += a[c*8+d]*vv[d];
      ob[(size_t)c*1024+n] += s;
    }
  }
}

// ===========================================================================
extern "C" void kernel_launch(void* const* d_in, const int* in_sizes, int n_in,
                              void* d_out, int out_size, void* d_ws, size_t ws_size,
                              hipStream_t stream)
{
  (void)in_sizes; (void)n_in; (void)out_size; (void)ws_size;
  const float* x      = (const float*)d_in[0];
  const float* y      = (const float*)d_in[1];
  const float* temp   = (const float*)d_in[2];
  const float* enc_w1 = (const float*)d_in[3];
  const float* enc_w2 = (const float*)d_in[4];
  const float* enc_w3 = (const float*)d_in[5];
  const float* kv_w   = (const float*)d_in[6];
  const float* kv_dw_w= (const float*)d_in[7];
  const float* q_w    = (const float*)d_in[8];
  const float* q_dw_w = (const float*)d_in[9];
  const float* proj_w = (const float*)d_in[10];
  const float* dec_w1 = (const float*)d_in[11];
  const float* dec_w2 = (const float*)d_in[12];
  const float* dec_w3 = (const float*)d_in[13];
  float* out = (float*)d_out;

  float* W   = (float*)d_ws;
  float* ST  = W;                    // 2048
  float* ST0 = ST;
  float* ST1 = ST + 128;
  float* ST2 = ST + 256;
  float* ST3 = ST + 512;
  float* ST4 = ST + 768;
  float* ST5 = ST + 1024;
  float* A    = W + 2048;            // 2,097,152-float region, multiply reused
  float* E1   = A;
  float* KV1  = A;
  float* QPre = A + 1048576;
  float* ATTN = A;
  float* PROJ = A + 524288;
  float* D1   = A + 1048576;
  float* E2   = W + 2099200;         //   524,288
  float* E3   = W + 2623488;         // 1,048,576
  float* KV   = W + 3672064;         // 1,048,576
  float* Q    = W + 4720640;         //   524,288
  float* DEN  = W + 5244928;         //    65,536
  float* D2   = W + 2099200;         // 4,194,304 (overlaps E2..DEN, dead then)

  const float inv32k = 1.f/32768.f, inv8k = 1.f/8192.f;

  hipMemsetAsync(ST, 0, 2048*sizeof(float), stream);
  hipMemsetAsync(DEN, 0, 65536*sizeof(float), stream);

  // ---- encoder ----
  conv1x1_enc1_kernel<<<dim3(64,16),256,0,stream>>>(x, y, enc_w1, E1, ST0);
  conv2x2s2_bn_kernel<<<dim3(8,4,16),256,0,stream>>>(E1, enc_w2, E2, ST0, ST1, inv32k);
  conv1x1_small<1,true,true><<<dim3(2,32,16),256,0,stream>>>(
      E2, E2 + (size_t)8*32*1024, enc_w3, E3, ST1, ST2, 32, 64, 0, 8, inv8k);

  // ---- kv = dw3x3(1x1(x_enc)); q = conv3x3(1x1(y_enc)) ----
  conv1x1_small<1,true,false><<<dim3(2,64,8),256,0,stream>>>(
      E3, E3, kv_w, KV1, ST2, nullptr, 64, 128, 0, 999, inv8k);
  dwconv3x3_kernel<<<dim3(4,128,8),256,0,stream>>>(KV1, kv_dw_w, KV, 128, 32, 32);
  conv1x1_small<1,true,false><<<dim3(2,32,8),256,0,stream>>>(
      E3 + (size_t)8*64*1024, E3, q_w, QPre, ST2 + 128, nullptr, 64, 64, 0, 999, inv8k);
  conv3x3_kernel<<<dim3(4,64,8),256,0,stream>>>(QPre, q_dw_w, Q, 64, 32, 32);

  // ATTN region (overlapping KV1/QPre) is dead now — zero for atomics
  hipMemsetAsync(ATTN, 0, 524288*sizeof(float), stream);

  // ---- l2 normalize q and k ----
  l2norm_kernel<<<1024,256,0,stream>>>(Q, KV);

  // ---- attention ----
  attn_pass1<<<dim3(16,8,8),256,0,stream>>>(Q, KV, temp, DEN);
  attn_pass2<<<dim3(16,8,8),256,0,stream>>>(Q, KV, temp, DEN, ATTN);
  attn_channel<<<dim3(8,8),256,0,stream>>>(Q, KV, temp, ATTN);

  // ---- proj ----
  conv1x1_small<1,false,false><<<dim3(2,32,8),256,0,stream>>>(
      ATTN, ATTN, proj_w, PROJ, nullptr, nullptr, 64, 64, 0, 999, 0.f);

  // ---- decoder ----
  conv1x1_small<1,false,true><<<dim3(2,64,8),256,0,stream>>>(
      PROJ, PROJ, dec_w1, D1, nullptr, ST3, 64, 128, 1, 999, 0.f);
  upsample2x2_bn_kernel<<<dim3(64,8),256,0,stream>>>(D1, dec_w2, D2, ST3, ST4, inv8k);
  conv1x1_kernel<8,true,true><<<dim3(4,32,8),256,0,stream>>>(
      D2, D2, dec_w3, out, ST4, ST5, 128, 256, 4096, 1, 999, inv32k);
  bn_final_kernel<<<8192,256,0,stream>>>(out, ST5, inv32k);
}

// Round 8
// 606.367 us; speedup vs baseline: 2.3781x; 1.0238x over previous
//
#include <hip/hip_runtime.h>
#include <hip/hip_bf16.h>

#define EPS_BN 1e-5f

// ===========================================================================
// enc1: double-buffered LDS-tiled GEMM. out[z,o,p] = sum_i w[o,i]*in[z,i,p]
// I=256, O=32, P=4096. Tile 64 cols x 32 outs; K chunks of 32.
// grid (64,16)=1024. launch_bounds(256,2): allow ~128 VGPR so the prefetch
// stays in registers (r7: compiler squeezed to 40 VGPR, killing the pipeline).
// ===========================================================================
__global__ __launch_bounds__(256,2) void conv1x1_enc1_kernel(
    const float* __restrict__ in0, const float* __restrict__ in1,
    const float* __restrict__ w, float* __restrict__ out,
    float* __restrict__ stOut)
{
  __shared__ float il[2][32*64];
  __shared__ float wt[2][32*34];
  int tid  = threadIdx.x;
  int tile = blockIdx.x;
  int z    = blockIdx.y;
  int t    = z >> 3;
  const float* in  = t ? in1 : in0;
  const float* inb = in + ((size_t)(z&7))*256*4096 + tile*64;
  int cg = tid & 15;
  int og = tid >> 4;

  float4 vr[2]; float wr[4];
  int chA = tid >> 4;
  int chB = 16 + chA;
  int wo  = tid >> 5;
  int wch = tid & 31;

  vr[0] = *(const float4*)(inb + (size_t)chA*4096 + cg*4);
  vr[1] = *(const float4*)(inb + (size_t)chB*4096 + cg*4);
#pragma unroll
  for(int u=0;u<4;u++) wr[u] = w[(size_t)(wo+u*8)*256 + wch];
  ((float4*)il[0])[tid]     = vr[0];
  ((float4*)il[0])[tid+256] = vr[1];
#pragma unroll
  for(int u=0;u<4;u++) wt[0][wch*34 + wo + u*8] = wr[u];
  __syncthreads();

  float acc[2][4];
#pragma unroll
  for(int j=0;j<2;j++){ acc[j][0]=acc[j][1]=acc[j][2]=acc[j][3]=0.f; }

  for(int c=0;c<8;c++){
    int cur = c & 1;
    if(c < 7){
      int k0 = (c+1)*32;
      vr[0] = *(const float4*)(inb + (size_t)(k0+chA)*4096 + cg*4);
      vr[1] = *(const float4*)(inb + (size_t)(k0+chB)*4096 + cg*4);
#pragma unroll
      for(int u=0;u<4;u++) wr[u] = w[(size_t)(wo+u*8)*256 + k0 + wch];
    }
    const float4* ilc = (const float4*)il[cur];
    const float*  wtc = wt[cur];
#pragma unroll 8
    for(int ch=0; ch<32; ch++){
      float4 v  = ilc[ch*16 + cg];
      float2 wv = *(const float2*)&wtc[ch*34 + og*2];
      acc[0][0]=fmaf(wv.x,v.x,acc[0][0]); acc[0][1]=fmaf(wv.x,v.y,acc[0][1]);
      acc[0][2]=fmaf(wv.x,v.z,acc[0][2]); acc[0][3]=fmaf(wv.x,v.w,acc[0][3]);
      acc[1][0]=fmaf(wv.y,v.x,acc[1][0]); acc[1][1]=fmaf(wv.y,v.y,acc[1][1]);
      acc[1][2]=fmaf(wv.y,v.z,acc[1][2]); acc[1][3]=fmaf(wv.y,v.w,acc[1][3]);
    }
    if(c < 7){
      int nxt = 1 - cur;
      ((float4*)il[nxt])[tid]     = vr[0];
      ((float4*)il[nxt])[tid+256] = vr[1];
#pragma unroll
      for(int u=0;u<4;u++) wt[nxt][wch*34 + wo + u*8] = wr[u];
      __syncthreads();
    }
  }

  float* ob = out + ((size_t)z*32 + og*2)*4096 + tile*64 + cg*4;
#pragma unroll
  for(int j=0;j<2;j++){
    float4 vv = {acc[j][0],acc[j][1],acc[j][2],acc[j][3]};
    *(float4*)(ob + (size_t)j*4096) = vv;
  }
#pragma unroll
  for(int j=0;j<2;j++){
    float s  = acc[j][0]+acc[j][1]+acc[j][2]+acc[j][3];
    float s2 = acc[j][0]*acc[j][0]+acc[j][1]*acc[j][1]
             + acc[j][2]*acc[j][2]+acc[j][3]*acc[j][3];
    for(int off=8; off>0; off>>=1){
      s  += __shfl_down(s,  off, 16);
      s2 += __shfl_down(s2, off, 16);
    }
    if(cg==0){
      atomicAdd(&stOut[((size_t)t*32 + og*2 + j)*2],   s);
      atomicAdd(&stOut[((size_t)t*32 + og*2 + j)*2+1], s2);
    }
  }
}

// ===========================================================================
// Generic big-P 1x1 conv (dec3, P=4096), 8-deep pipelined loads.
// ===========================================================================
template<int OT, bool HASBN, bool HASSTATS>
__global__ __launch_bounds__(256) void conv1x1_kernel(
    const float* __restrict__ in0, const float* __restrict__ in1,
    const float* __restrict__ w, float* __restrict__ out,
    const float* __restrict__ stIn, float* __restrict__ stOut,
    int I, int O, int P, int wio, int zsplit, float invN)
{
  __shared__ float wl[2048];
  __shared__ float bnm[256], bnr[256];
  int tid = threadIdx.x;
  int o0 = blockIdx.y*OT;
  int z  = blockIdx.z;
  int t  = (z >= zsplit) ? 1 : 0;
  int b  = t ? (z - zsplit) : z;
  const float* in = t ? in1 : in0;

  for(int idx=tid; idx<I*OT; idx+=256){
    int i = idx/OT, j = idx - i*OT;
    wl[idx] = wio ? w[(size_t)i*O + o0 + j] : w[(size_t)(o0+j)*I + i];
  }
  if(HASBN){
    for(int i=tid; i<I; i+=256){
      float s  = stIn[((size_t)t*I + i)*2];
      float s2 = stIn[((size_t)t*I + i)*2+1];
      float m  = s*invN;
      bnm[i] = m;
      bnr[i] = rsqrtf(s2*invN - m*m + EPS_BN);
    }
  }
  __syncthreads();

  int p4 = blockIdx.x*256 + tid;
  const float4* inb = (const float4*)(in + (size_t)b*I*P) + p4;
  int P4 = P >> 2;

  float acc[OT][4];
#pragma unroll
  for(int j=0;j<OT;j++){ acc[j][0]=acc[j][1]=acc[j][2]=acc[j][3]=0.f; }

  float4 vb[8];
  for(int i0=0;i0<I;i0+=8){
#pragma unroll
    for(int u=0;u<8;u++) vb[u] = inb[(size_t)(i0+u)*P4];
#pragma unroll
    for(int u=0;u<8;u++){
      float4 v = vb[u];
      if(HASBN){
        float m = bnm[i0+u], r = bnr[i0+u];
        v.x = fmaxf((v.x-m)*r, 0.f); v.y = fmaxf((v.y-m)*r, 0.f);
        v.z = fmaxf((v.z-m)*r, 0.f); v.w = fmaxf((v.w-m)*r, 0.f);
      }
      const float* wr = &wl[(i0+u)*OT];
#pragma unroll
      for(int j=0;j<OT;j++){
        float wv = wr[j];
        acc[j][0] = fmaf(wv, v.x, acc[j][0]);
        acc[j][1] = fmaf(wv, v.y, acc[j][1]);
        acc[j][2] = fmaf(wv, v.z, acc[j][2]);
        acc[j][3] = fmaf(wv, v.w, acc[j][3]);
      }
    }
  }

  float4* ob = (float4*)(out + ((size_t)z*O + o0)*P) + p4;
#pragma unroll
  for(int j=0;j<OT;j++){
    float4 vv = {acc[j][0], acc[j][1], acc[j][2], acc[j][3]};
    ob[(size_t)j*P4] = vv;
  }

  if(HASSTATS){
#pragma unroll
    for(int j=0;j<OT;j++){
      float s  = acc[j][0]+acc[j][1]+acc[j][2]+acc[j][3];
      float s2 = acc[j][0]*acc[j][0]+acc[j][1]*acc[j][1]
               + acc[j][2]*acc[j][2]+acc[j][3]*acc[j][3];
      for(int off=32; off>0; off>>=1){
        s  += __shfl_down(s,  off, 64);
        s2 += __shfl_down(s2, off, 64);
      }
      if((tid & 63)==0){
        atomicAdd(&stOut[((size_t)t*O + o0 + j)*2],   s);
        atomicAdd(&stOut[((size_t)t*O + o0 + j)*2+1], s2);
      }
    }
  }
}

// ===========================================================================
// Small-P (P=1024) 1x1 conv: 128 f4-cols x 2 o-slices. 8-deep pipeline.
// ===========================================================================
template<int OT, bool HASBN, bool HASSTATS>
__global__ __launch_bounds__(256) void conv1x1_small(
    const float* __restrict__ in0, const float* __restrict__ in1,
    const float* __restrict__ w, float* __restrict__ out,
    const float* __restrict__ stIn, float* __restrict__ stOut,
    int I, int O, int wio, int zsplit, float invN)
{
  __shared__ float wl[512];
  __shared__ float bnm[128], bnr[128];
  int tid = threadIdx.x;
  int z  = blockIdx.z;
  int t  = (z >= zsplit) ? 1 : 0;
  int b  = t ? (z - zsplit) : z;
  const float* in = t ? in1 : in0;
  int W2 = 2*OT;

  for(int idx=tid; idx<I*W2; idx+=256){
    int i = idx/W2, slot = idx - i*W2;
    int oabs = blockIdx.y*W2 + slot;
    wl[idx] = wio ? w[(size_t)i*O + oabs] : w[(size_t)oabs*I + i];
  }
  if(HASBN){
    for(int i=tid; i<I; i+=256){
      float s  = stIn[((size_t)t*I + i)*2];
      float s2 = stIn[((size_t)t*I + i)*2+1];
      float m  = s*invN;
      bnm[i] = m;
      bnr[i] = rsqrtf(s2*invN - m*m + EPS_BN);
    }
  }
  __syncthreads();

  int p4 = blockIdx.x*128 + (tid & 127);
  int os = tid >> 7;
  const float4* inb = (const float4*)(in + (size_t)b*I*1024) + p4;

  float acc[OT][4];
#pragma unroll
  for(int j=0;j<OT;j++){ acc[j][0]=acc[j][1]=acc[j][2]=acc[j][3]=0.f; }

  float4 vb[8];
  for(int i0=0;i0<I;i0+=8){
#pragma unroll
    for(int u=0;u<8;u++) vb[u] = inb[(size_t)(i0+u)*256];
#pragma unroll
    for(int u=0;u<8;u++){
      float4 v = vb[u];
      if(HASBN){
        float m = bnm[i0+u], r = bnr[i0+u];
        v.x = fmaxf((v.x-m)*r, 0.f); v.y = fmaxf((v.y-m)*r, 0.f);
        v.z = fmaxf((v.z-m)*r, 0.f); v.w = fmaxf((v.w-m)*r, 0.f);
      }
      const float* wr = &wl[(i0+u)*W2 + os*OT];
#pragma unroll
      for(int j=0;j<OT;j++){
        float wv = wr[j];
        acc[j][0] = fmaf(wv, v.x, acc[j][0]);
        acc[j][1] = fmaf(wv, v.y, acc[j][1]);
        acc[j][2] = fmaf(wv, v.z, acc[j][2]);
        acc[j][3] = fmaf(wv, v.w, acc[j][3]);
      }
    }
  }

  int obase = blockIdx.y*W2 + os*OT;
  float4* ob = (float4*)(out + ((size_t)z*O + obase)*1024) + p4;
#pragma unroll
  for(int j=0;j<OT;j++){
    float4 vv = {acc[j][0], acc[j][1], acc[j][2], acc[j][3]};
    ob[(size_t)j*256] = vv;
  }

  if(HASSTATS){
#pragma unroll
    for(int j=0;j<OT;j++){
      float s  = acc[j][0]+acc[j][1]+acc[j][2]+acc[j][3];
      float s2 = acc[j][0]*acc[j][0]+acc[j][1]*acc[j][1]
               + acc[j][2]*acc[j][2]+acc[j][3]*acc[j][3];
      for(int off=32; off>0; off>>=1){
        s  += __shfl_down(s,  off, 64);
        s2 += __shfl_down(s2, off, 64);
      }
      if((tid & 63)==0){
        atomicAdd(&stOut[((size_t)t*O + obase + j)*2],   s);
        atomicAdd(&stOut[((size_t)t*O + obase + j)*2+1], s2);
      }
    }
  }
}

// ===========================================================================
// Encoder k=2 s=2 conv (unchanged from round 7)
// ===========================================================================
__global__ __launch_bounds__(256) void conv2x2s2_bn_kernel(
    const float* __restrict__ in, const float* __restrict__ w,
    float* __restrict__ out, const float* __restrict__ stIn,
    float* __restrict__ stOut, float invN)
{
  __shared__ float wl[512];
  __shared__ float bnm[32], bnr[32];
  int tid = threadIdx.x;
  int o0 = blockIdx.x*4;
  int rq = blockIdx.y;
  int z  = blockIdx.z;
  int t  = z >> 3;

  for(int idx=tid; idx<512; idx+=256){
    int osub = idx>>7, ch=(idx>>2)&31, pq=idx&3;
    wl[idx] = w[(((size_t)(o0+osub)*32 + ch)*4) + pq];
  }
  if(tid < 32){
    float s  = stIn[((size_t)t*32 + tid)*2];
    float s2 = stIn[((size_t)t*32 + tid)*2+1];
    float m  = s*invN;
    bnm[tid] = m;
    bnr[tid] = rsqrtf(s2*invN - m*m + EPS_BN);
  }
  __syncthreads();

  int os   = tid >> 6;
  int slot = tid & 63;
  int h    = rq*8 + (slot>>3);
  int wg   = slot & 7;
  int cb   = wg*8;
  const float* wbase = &wl[os*128];
  const float* inz = in + (size_t)z*32*4096;

  float acc[4] = {0,0,0,0};
  float4 c0,c1,c2,c3, n0_,n1_,n2_,n3_;
  c0 = *(const float4*)(inz + (size_t)0*4096 + (2*h)*64 + cb);
  c1 = *(const float4*)(inz + (size_t)0*4096 + (2*h)*64 + cb + 4);
  c2 = *(const float4*)(inz + (size_t)0*4096 + (2*h+1)*64 + cb);
  c3 = *(const float4*)(inz + (size_t)0*4096 + (2*h+1)*64 + cb + 4);
  for(int ch=0; ch<32; ch++){
    if(ch < 31){
      n0_ = *(const float4*)(inz + (size_t)(ch+1)*4096 + (2*h)*64 + cb);
      n1_ = *(const float4*)(inz + (size_t)(ch+1)*4096 + (2*h)*64 + cb + 4);
      n2_ = *(const float4*)(inz + (size_t)(ch+1)*4096 + (2*h+1)*64 + cb);
      n3_ = *(const float4*)(inz + (size_t)(ch+1)*4096 + (2*h+1)*64 + cb + 4);
    }
    float m = bnm[ch], r = bnr[ch];
    float t0[8] = {c0.x,c0.y,c0.z,c0.w,c1.x,c1.y,c1.z,c1.w};
    float t1[8] = {c2.x,c2.y,c2.z,c2.w,c3.x,c3.y,c3.z,c3.w};
#pragma unroll
    for(int e=0;e<8;e++){
      t0[e] = fmaxf((t0[e]-m)*r, 0.f);
      t1[e] = fmaxf((t1[e]-m)*r, 0.f);
    }
    const float* wp = wbase + ch*4;
#pragma unroll
    for(int k=0;k<4;k++){
      acc[k] = fmaf(wp[0], t0[2*k],   acc[k]);
      acc[k] = fmaf(wp[1], t0[2*k+1], acc[k]);
      acc[k] = fmaf(wp[2], t1[2*k],   acc[k]);
      acc[k] = fmaf(wp[3], t1[2*k+1], acc[k]);
    }
    c0=n0_; c1=n1_; c2=n2_; c3=n3_;
  }

  float4 vv = {acc[0],acc[1],acc[2],acc[3]};
  *(float4*)(out + ((size_t)z*32 + o0+os)*1024 + h*32 + wg*4) = vv;

  float s  = acc[0]+acc[1]+acc[2]+acc[3];
  float s2 = acc[0]*acc[0]+acc[1]*acc[1]+acc[2]*acc[2]+acc[3]*acc[3];
  for(int off=32; off>0; off>>=1){
    s  += __shfl_down(s,  off, 64);
    s2 += __shfl_down(s2, off, 64);
  }
  if((tid & 63)==0){
    atomicAdd(&stOut[((size_t)t*32 + o0 + os)*2],   s);
    atomicAdd(&stOut[((size_t)t*32 + o0 + os)*2+1], s2);
  }
}

// ===========================================================================
// ConvTranspose k=2 s=2 (unchanged)
// ===========================================================================
__global__ __launch_bounds__(256) void upsample2x2_bn_kernel(
    const float* __restrict__ in, const float* __restrict__ w,
    float* __restrict__ out, const float* __restrict__ stIn,
    float* __restrict__ stOut, float invN)
{
  __shared__ float wl[1024];
  __shared__ float bnm[128], bnr[128];
  int tid = threadIdx.x;
  int o0 = blockIdx.x*2;
  int b  = blockIdx.y;

  for(int idx=tid; idx<1024; idx+=256){
    int pq = idx & 3, r = idx >> 2;
    int i = r >> 1, j = r & 1;
    wl[idx] = w[((size_t)i*128 + o0+j)*4 + pq];
  }
  if(tid < 128){
    float s  = stIn[(size_t)tid*2];
    float s2 = stIn[(size_t)tid*2+1];
    float m  = s*invN;
    bnm[tid] = m;
    bnr[tid] = rsqrtf(s2*invN - m*m + EPS_BN);
  }
  __syncthreads();

  int h  = tid >> 3;
  int wg = tid & 7;
  int w0 = wg*4;

  float acc[2][16];
#pragma unroll
  for(int j=0;j<2;j++) for(int e=0;e<16;e++) acc[j][e]=0.f;

  float4 vb4[8];
  for(int i0=0;i0<128;i0+=8){
#pragma unroll
    for(int u=0;u<8;u++)
      vb4[u] = *(const float4*)(in + (((size_t)b*128+i0+u)*1024) + h*32 + w0);
#pragma unroll
    for(int u=0;u<8;u++){
      int i = i0+u;
      float4 v = vb4[u];
      float m = bnm[i], r = bnr[i];
      float vk[4] = {fmaxf((v.x-m)*r,0.f), fmaxf((v.y-m)*r,0.f),
                     fmaxf((v.z-m)*r,0.f), fmaxf((v.w-m)*r,0.f)};
#pragma unroll
      for(int j=0;j<2;j++){
        const float* wj = &wl[(i*2+j)*4];
#pragma unroll
        for(int pq=0;pq<4;pq++){
#pragma unroll
          for(int k=0;k<4;k++)
            acc[j][pq*4+k] = fmaf(wj[pq], vk[k], acc[j][pq*4+k]);
        }
      }
    }
  }

#pragma unroll
  for(int j=0;j<2;j++){
    float* ob = out + ((size_t)b*128 + o0+j)*4096;
#pragma unroll
    for(int p=0;p<2;p++){
      float4 A = {acc[j][(p*2+0)*4+0], acc[j][(p*2+1)*4+0],
                  acc[j][(p*2+0)*4+1], acc[j][(p*2+1)*4+1]};
      float4 B = {acc[j][(p*2+0)*4+2], acc[j][(p*2+1)*4+2],
                  acc[j][(p*2+0)*4+3], acc[j][(p*2+1)*4+3]};
      *(float4*)(ob + (2*h+p)*64 + 2*w0)     = A;
      *(float4*)(ob + (2*h+p)*64 + 2*w0 + 4) = B;
    }
  }

#pragma unroll
  for(int j=0;j<2;j++){
    float s=0.f, s2=0.f;
#pragma unroll
    for(int e=0;e<16;e++){ s += acc[j][e]; s2 += acc[j][e]*acc[j][e]; }
    for(int off=32; off>0; off>>=1){
      s  += __shfl_down(s,  off, 64);
      s2 += __shfl_down(s2, off, 64);
    }
    if((tid & 63)==0){
      atomicAdd(&stOut[((size_t)(o0+j))*2],   s);
      atomicAdd(&stOut[((size_t)(o0+j))*2+1], s2);
    }
  }
}

// ===========================================================================
__global__ __launch_bounds__(256) void bn_final_kernel(
    float* __restrict__ x, const float* __restrict__ st, float invN)
{
  int idx4 = blockIdx.x*256 + threadIdx.x;
  int c = (idx4 >> 10) & 255;
  float s  = st[(size_t)c*2];
  float s2 = st[(size_t)c*2+1];
  float m  = s*invN;
  float r  = rsqrtf(s2*invN - m*m + EPS_BN);
  float4 v = ((float4*)x)[idx4];
  v.x = fmaxf((v.x-m)*r, 0.f); v.y = fmaxf((v.y-m)*r, 0.f);
  v.z = fmaxf((v.z-m)*r, 0.f); v.w = fmaxf((v.w-m)*r, 0.f);
  ((float4*)x)[idx4] = v;
}

// ===========================================================================
// depthwise 3x3, pad 1, f4 per thread, whole 32x32 per (c,b). grid (C,B).
// ===========================================================================
__global__ __launch_bounds__(256) void dwconv3x3_kernel(
    const float* __restrict__ in, const float* __restrict__ w,
    float* __restrict__ out, int C)
{
  int c = blockIdx.x, b = blockIdx.y;
  int tid = threadIdx.x;
  __shared__ float wl[9];
  if(tid < 9) wl[tid] = w[c*9 + tid];
  __syncthreads();
  int h = tid >> 3, x4 = tid & 7;
  int c0 = x4*4;
  const float* base = in + ((size_t)b*C + c)*1024;
  float ax=0.f, ay=0.f, az=0.f, aw=0.f;
#pragma unroll
  for(int dr=0; dr<3; dr++){
    int r = h + dr - 1;
    if((unsigned)r >= 32u) continue;
    const float* row = base + r*32 + c0;
    float4 cc = *(const float4*)row;
    float l  = (x4>0) ? row[-1] : 0.f;
    float rr = (x4<7) ? row[4]  : 0.f;
    float w0=wl[dr*3], w1=wl[dr*3+1], w2=wl[dr*3+2];
    ax = fmaf(w0,l,   fmaf(w1,cc.x, fmaf(w2,cc.y, ax)));
    ay = fmaf(w0,cc.x,fmaf(w1,cc.y, fmaf(w2,cc.z, ay)));
    az = fmaf(w0,cc.y,fmaf(w1,cc.z, fmaf(w2,cc.w, az)));
    aw = fmaf(w0,cc.z,fmaf(w1,cc.w, fmaf(w2,rr,  aw)));
  }
  float4 vv = {ax,ay,az,aw};
  *(float4*)(out + ((size_t)b*C + c)*1024 + h*32 + c0) = vv;
}

// ===========================================================================
// full 3x3 conv, pad 1, f4 per thread, whole 32x32 per (o,b). grid (O,B).
// w[o,i,3,3]; weights in LDS (uniform reads -> broadcast).
// ===========================================================================
__global__ __launch_bounds__(256) void conv3x3_kernel(
    const float* __restrict__ in, const float* __restrict__ w,
    float* __restrict__ out, int IC)
{
  int o = blockIdx.x, b = blockIdx.y;
  int tid = threadIdx.x;
  __shared__ float wl[576];
  for(int t=tid; t<IC*9; t+=256) wl[t] = w[(size_t)o*IC*9 + t];
  __syncthreads();
  int h = tid >> 3, x4 = tid & 7;
  int c0 = x4*4;
  const float* inb = in + (size_t)b*IC*1024;
  float ax=0.f, ay=0.f, az=0.f, aw=0.f;
#pragma unroll 2
  for(int i=0;i<IC;i++){
    const float* base = inb + (size_t)i*1024;
    const float* wp = &wl[i*9];
#pragma unroll
    for(int dr=0; dr<3; dr++){
      int r = h + dr - 1;
      if((unsigned)r >= 32u) continue;
      const float* row = base + r*32 + c0;
      float4 cc = *(const float4*)row;
      float l  = (x4>0) ? row[-1] : 0.f;
      float rr = (x4<7) ? row[4]  : 0.f;
      float w0=wp[dr*3], w1=wp[dr*3+1], w2=wp[dr*3+2];
      ax = fmaf(w0,l,   fmaf(w1,cc.x, fmaf(w2,cc.y, ax)));
      ay = fmaf(w0,cc.x,fmaf(w1,cc.y, fmaf(w2,cc.z, ay)));
      az = fmaf(w0,cc.y,fmaf(w1,cc.z, fmaf(w2,cc.w, az)));
      aw = fmaf(w0,cc.z,fmaf(w1,cc.w, fmaf(w2,rr,  aw)));
    }
  }
  float4 vv = {ax,ay,az,aw};
  *(float4*)(out + ((size_t)b*gridDim.x + o)*1024 + h*32 + c0) = vv;
}

// ===========================================================================
// Row norms only: scl[r] = 1/max(||row||,1e-12). r<512: q rows; else k rows.
// ===========================================================================
__global__ __launch_bounds__(256) void norm_scale_kernel(
    const float* __restrict__ q, const float* __restrict__ kv,
    float* __restrict__ scl)
{
  int r = blockIdx.x;
  const float* p;
  if(r < 512){ int b=r>>6, c=r&63; p = q + ((size_t)b*64+c)*1024; }
  else { int rr=r-512; int b=rr>>6, c=rr&63; p = kv + ((size_t)b*128+c)*1024; }
  int tid = threadIdx.x;
  float4 v = ((const float4*)p)[tid];
  float s = v.x*v.x + v.y*v.y + v.z*v.z + v.w*v.w;
  __shared__ float ls[256];
  ls[tid]=s; __syncthreads();
  for(int st=128; st>0; st>>=1){ if(tid<st) ls[tid]+=ls[tid+st]; __syncthreads(); }
  if(tid==0) scl[r] = 1.f/fmaxf(sqrtf(ls[0]), 1e-12f);
}

// ===========================================================================
// Spatial attention pass 1 (norm scales applied on load). grid (16,8,8).
// ===========================================================================
__global__ __launch_bounds__(256) void attn_pass1(
    const float* __restrict__ q, const float* __restrict__ kv,
    const float* __restrict__ temp, const float* __restrict__ scl,
    float* __restrict__ den_out)
{
  int bx = blockIdx.x, hh = blockIdx.y, b = blockIdx.z;
  int nchunk = bx >> 2, mq = bx & 3;
  int tid = threadIdx.x;
  __shared__ __align__(16) float kl[256*12];
  const float* kb = kv + ((size_t)b*128 + hh*8)*1024 + mq*256;
  for(int t=tid;t<2048;t+=256){
    int c=t>>8, m=t&255;
    kl[m*12+c] = kb[(size_t)c*1024+m] * scl[512 + b*64 + hh*8 + c];
  }
  __syncthreads();
  int n = nchunk*256 + tid;
  const float* qp = q + ((size_t)b*64 + hh*8)*1024 + n;
  float th = temp[hh];
  float mxb = fabsf(th);
  float qr[8];
#pragma unroll
  for(int c=0;c<8;c++) qr[c] = qp[(size_t)c*1024] * scl[b*64+hh*8+c] * th;
  const float4* kl4 = (const float4*)kl;
  float den = 0.f, den2 = 0.f;
  for(int m=0;m<256;m+=2){
    float4 a  = kl4[m*3],     a2 = kl4[m*3+1];
    float4 bt = kl4[(m+1)*3], b2 = kl4[(m+1)*3+1];
    float s0 = qr[0]*a.x+qr[1]*a.y+qr[2]*a.z+qr[3]*a.w
             + qr[4]*a2.x+qr[5]*a2.y+qr[6]*a2.z+qr[7]*a2.w;
    float s1 = qr[0]*bt.x+qr[1]*bt.y+qr[2]*bt.z+qr[3]*bt.w
             + qr[4]*b2.x+qr[5]*b2.y+qr[6]*b2.z+qr[7]*b2.w;
    den  += __expf(s0 - mxb);
    den2 += __expf(s1 - mxb);
  }
  atomicAdd(&den_out[((size_t)(b*8+hh))*1024+n], den+den2);
}

// ===========================================================================
// Spatial attention pass 2 (norm scales applied on load). grid (16,8,8).
// ===========================================================================
__global__ __launch_bounds__(256) void attn_pass2(
    const float* __restrict__ q, const float* __restrict__ kv,
    const float* __restrict__ temp, const float* __restrict__ scl,
    const float* __restrict__ den, float* __restrict__ out)
{
  int bx = blockIdx.x, hh = blockIdx.y, b = blockIdx.z;
  int mchunk = bx >> 2, nq = bx & 3;
  int tid = threadIdx.x;
  __shared__ __align__(16) float ql[256*12];
  __shared__ __align__(16) float vl[256*12];
  __shared__ float idl[256];
  int bh = b*8+hh;
  int n0 = nq*256;
  const float* qb = q  + ((size_t)b*64 + hh*8)*1024 + n0;
  const float* vb = kv + ((size_t)b*128 + 64 + hh*8)*1024 + n0;
  for(int t=tid;t<2048;t+=256){
    int c=t>>8, n=t&255;
    ql[n*12+c] = qb[(size_t)c*1024+n] * scl[b*64+hh*8+c];
    vl[n*12+c] = vb[(size_t)c*1024+n];
  }
  idl[tid] = 1.f/den[(size_t)bh*1024 + n0 + tid];
  __syncthreads();
  int m = mchunk*256 + tid;
  const float* kb = kv + ((size_t)b*128 + hh*8)*1024 + m;
  float th = temp[hh];
  float mxb = fabsf(th);
  float kr[8];
#pragma unroll
  for(int c=0;c<8;c++) kr[c] = kb[(size_t)c*1024] * scl[512+b*64+hh*8+c] * th;
  float acc[8] = {0,0,0,0,0,0,0,0};
  const float4* ql4 = (const float4*)ql;
  const float4* vl4 = (const float4*)vl;
  for(int n=0;n<256;n+=2){
    float4 qa = ql4[n*3],     qa2 = ql4[n*3+1];
    float4 qc = ql4[(n+1)*3], qc2 = ql4[(n+1)*3+1];
    float s0 = kr[0]*qa.x+kr[1]*qa.y+kr[2]*qa.z+kr[3]*qa.w
             + kr[4]*qa2.x+kr[5]*qa2.y+kr[6]*qa2.z+kr[7]*qa2.w;
    float s1 = kr[0]*qc.x+kr[1]*qc.y+kr[2]*qc.z+kr[3]*qc.w
             + kr[4]*qc2.x+kr[5]*qc2.y+kr[6]*qc2.z+kr[7]*qc2.w;
    float p0 = __expf(s0 - mxb) * idl[n];
    float p1 = __expf(s1 - mxb) * idl[n+1];
    float4 va = vl4[n*3],     va2 = vl4[n*3+1];
    float4 vc = vl4[(n+1)*3], vc2 = vl4[(n+1)*3+1];
    acc[0]+=p0*va.x + p1*vc.x; acc[1]+=p0*va.y + p1*vc.y;
    acc[2]+=p0*va.z + p1*vc.z; acc[3]+=p0*va.w + p1*vc.w;
    acc[4]+=p0*va2.x + p1*vc2.x; acc[5]+=p0*va2.y + p1*vc2.y;
    acc[6]+=p0*va2.z + p1*vc2.z; acc[7]+=p0*va2.w + p1*vc2.w;
  }
  float* ob = out + ((size_t)b*64 + hh*8)*1024 + m;
#pragma unroll
  for(int c=0;c<8;c++) atomicAdd(&ob[(size_t)c*1024], acc[c]);
}

// ===========================================================================
// Channel attention; gram scaled by qs[c]*ks[d]*t post-reduction. grid (8,8).
// ===========================================================================
__global__ __launch_bounds__(256) void attn_channel(
    const float* __restrict__ q, const float* __restrict__ kv,
    const float* __restrict__ temp, const float* __restrict__ scl,
    float* out)
{
  int hh = blockIdx.x, b = blockIdx.y;
  __shared__ float kl[8192];
  const float* qb = q  + ((size_t)b*64 + hh*8)*1024;
  const float* kb = kv + ((size_t)b*128 + hh*8)*1024;
  const float* vb = kv + ((size_t)b*128 + 64 + hh*8)*1024;
  int tid = threadIdx.x;
  for(int t=tid;t<8192;t+=256) kl[t]=kb[t];
  __syncthreads();
  __shared__ float part[256];
  __shared__ float a[64];
  {
    int pair = tid >> 2, seg = tid & 3;
    int c = pair >> 3, d = pair & 7;
    const float* qrow = qb + (size_t)c*1024 + seg*256;
    const float* krow = kl + d*1024 + seg*256;
    float s = 0.f;
#pragma unroll 4
    for(int n=0;n<256;n++) s += qrow[n]*krow[n];
    part[tid] = s;
  }
  __syncthreads();
  if(tid < 64){
    int c = tid >> 3, d = tid & 7;
    float g = part[tid*4]+part[tid*4+1]+part[tid*4+2]+part[tid*4+3];
    part[tid] = g * scl[b*64+hh*8+c] * scl[512+b*64+hh*8+d] * temp[hh];
  }
  __syncthreads();
  if(tid < 8){
    float mx = -3.4e38f;
    for(int d=0;d<8;d++) mx = fmaxf(mx, part[tid*8+d]);
    float den = 0.f;
    float e[8];
    for(int d=0;d<8;d++){ e[d] = __expf(part[tid*8+d]-mx); den+=e[d]; }
    float inv = 1.f/den;
    for(int d=0;d<8;d++) a[tid*8+d] = e[d]*inv;
  }
  __syncthreads();
  float* ob = out + ((size_t)b*64 + hh*8)*1024;
  for(int n=tid;n<1024;n+=256){
    float vv[8];
#pragma unroll
    for(int d=0;d<8;d++) vv[d] = vb[(size_t)d*1024+n];
#pragma unroll
    for(int c=0;c<8;c++){
      float s = 0.f;
#pragma unroll
      for(int d=0;d<8;d++) s += a[c*8+d]*vv[d];
      ob[(size_t)c*1024+n] += s;
    }
  }
}

// ===========================================================================
extern "C" void kernel_launch(void* const* d_in, const int* in_sizes, int n_in,
                              void* d_out, int out_size, void* d_ws, size_t ws_size,
                              hipStream_t stream)
{
  (void)in_sizes; (void)n_in; (void)out_size; (void)ws_size;
  const float* x      = (const float*)d_in[0];
  const float* y      = (const float*)d_in[1];
  const float* temp   = (const float*)d_in[2];
  const float* enc_w1 = (const float*)d_in[3];
  const float* enc_w2 = (const float*)d_in[4];
  const float* enc_w3 = (const float*)d_in[5];
  const float* kv_w   = (const float*)d_in[6];
  const float* kv_dw_w= (const float*)d_in[7];
  const float* q_w    = (const float*)d_in[8];
  const float* q_dw_w = (const float*)d_in[9];
  const float* proj_w = (const float*)d_in[10];
  const float* dec_w1 = (const float*)d_in[11];
  const float* dec_w2 = (const float*)d_in[12];
  const float* dec_w3 = (const float*)d_in[13];
  float* out = (float*)d_out;

  float* W   = (float*)d_ws;
  float* ST  = W;                    // 2048
  float* ST0 = ST;
  float* ST1 = ST + 128;
  float* ST2 = ST + 256;
  float* ST3 = ST + 512;
  float* ST4 = ST + 768;
  float* ST5 = ST + 1024;
  float* A    = W + 2048;            // 2,097,152-float region, multiply reused
  float* E1   = A;
  float* KV1  = A;
  float* QPre = A + 1048576;
  float* ATTN = A;
  float* PROJ = A + 524288;
  float* D1   = A + 1048576;
  float* E2   = W + 2099200;         //   524,288
  float* E3   = W + 2623488;         // 1,048,576
  float* KV   = W + 3672064;         // 1,048,576
  float* Q    = W + 4720640;         //   524,288
  float* SCL  = W + 5244928;         //     1,024 (q/k reciprocal norms)
  float* DEN  = W + 5245952;         //    65,536
  float* D2   = W + 2099200;         // 4,194,304 (overlaps E2..DEN, dead then)

  const float inv32k = 1.f/32768.f, inv8k = 1.f/8192.f;

  hipMemsetAsync(ST, 0, 2048*sizeof(float), stream);
  hipMemsetAsync(DEN, 0, 65536*sizeof(float), stream);

  // ---- encoder ----
  conv1x1_enc1_kernel<<<dim3(64,16),256,0,stream>>>(x, y, enc_w1, E1, ST0);
  conv2x2s2_bn_kernel<<<dim3(8,4,16),256,0,stream>>>(E1, enc_w2, E2, ST0, ST1, inv32k);
  conv1x1_small<1,true,true><<<dim3(2,32,16),256,0,stream>>>(
      E2, E2 + (size_t)8*32*1024, enc_w3, E3, ST1, ST2, 32, 64, 0, 8, inv8k);

  // ---- kv = dw3x3(1x1(x_enc)); q = conv3x3(1x1(y_enc)) ----
  conv1x1_small<1,true,false><<<dim3(2,64,8),256,0,stream>>>(
      E3, E3, kv_w, KV1, ST2, nullptr, 64, 128, 0, 999, inv8k);
  dwconv3x3_kernel<<<dim3(128,8),256,0,stream>>>(KV1, kv_dw_w, KV, 128);
  conv1x1_small<1,true,false><<<dim3(2,32,8),256,0,stream>>>(
      E3 + (size_t)8*64*1024, E3, q_w, QPre, ST2 + 128, nullptr, 64, 64, 0, 999, inv8k);
  conv3x3_kernel<<<dim3(64,8),256,0,stream>>>(QPre, q_dw_w, Q, 64);

  // ATTN region (overlapping KV1/QPre) dead now — zero for atomics
  hipMemsetAsync(ATTN, 0, 524288*sizeof(float), stream);

  // ---- q/k row norms (scales only; tensors stay raw) ----
  norm_scale_kernel<<<1024,256,0,stream>>>(Q, KV, SCL);

  // ---- attention ----
  attn_pass1<<<dim3(16,8,8),256,0,stream>>>(Q, KV, temp, SCL, DEN);
  attn_pass2<<<dim3(16,8,8),256,0,stream>>>(Q, KV, temp, SCL, DEN, ATTN);
  attn_channel<<<dim3(8,8),256,0,stream>>>(Q, KV, temp, SCL, ATTN);

  // ---- proj ----
  conv1x1_small<1,false,false><<<dim3(2,32,8),256,0,stream>>>(
      ATTN, ATTN, proj_w, PROJ, nullptr, nullptr, 64, 64, 0, 999, 0.f);

  // ---- decoder ----
  conv1x1_small<1,false,true><<<dim3(2,64,8),256,0,stream>>>(
      PROJ, PROJ, dec_w1, D1, nullptr, ST3, 64, 128, 1, 999, 0.f);
  upsample2x2_bn_kernel<<<dim3(64,8),256,0,stream>>>(D1, dec_w2, D2, ST3, ST4, inv8k);
  conv1x1_kernel<8,true,true><<<dim3(4,32,8),256,0,stream>>>(
      D2, D2, dec_w3, out, ST4, ST5, 128, 256, 4096, 1, 999, inv32k);
  bn_final_kernel<<<8192,256,0,stream>>>(out, ST5, inv32k);
}